// Round 5
// baseline (1146.874 us; speedup 1.0000x reference)
//
#include <hip/hip_runtime.h>
#include <hip/hip_bf16.h>

// ---------------------------------------------------------------------------
// Sparse 3-level U-Net — Round 22: BN-plumbing fusion.
// R19/R20/R21 bracketed conv sync structures; big convs flat at 80-100us.
// Budget analysis: 55 launches; 12 bn_stats full-tensor scans + 11 bnact
// passes + gaps ~ 200-300us of the 899. R22:
//  (a) bn_stats fused into every conv epilogue (f32 acc partials, LDS tree
//      reduce into weight-LDS scratch, one f32 partial/block; deterministic).
//  (b) bnact fused into single-read consumers (d0,d1,u1,u0 gathers).
//  (c) 9 wprep -> 1 kernel; paired acts merged (bn2_1, bn2_0).
// Conv structure itself = R21 phase-staged (unchanged).
// Baseline R21: 898.9 us (y1 81 us). Prediction: ~720-770 us.
// ---------------------------------------------------------------------------

typedef __hip_bfloat16 hbf;
typedef __attribute__((ext_vector_type(8))) short short8;
typedef __attribute__((ext_vector_type(4))) float f32x4;
typedef const __attribute__((address_space(1))) short gas_short;
typedef __attribute__((address_space(3))) short las_short;

__device__ inline float b2f(short s) {
    unsigned u = ((unsigned)(unsigned short)s) << 16;
    float f; __builtin_memcpy(&f, &u, 4); return f;
}
__device__ inline short f2b(float f) {
    hbf h = __float2bfloat16(f);
    short s; __builtin_memcpy(&s, &h, 2); return s;
}

// ---------- weight prep: all 9 layers in one launch ------------------------
// wf[(((k*NCH + c)*NT + t)*64 + lane)*8 + j] = w[k][c*32+(lane>>4)*8+j][t*16+(lane&15)]
struct WPA {
    const float* src[9];
    short* dst[9];
    int K[9], CI[9], CO[9];
    int cum[10];
};
__global__ __launch_bounds__(256) void wprep_all(WPA a, int total) {
    int e0 = blockIdx.x * 256 + threadIdx.x;
    if (e0 >= total) return;
    int L = 0;
#pragma unroll
    for (int i = 1; i < 9; i++) L += (e0 >= a.cum[i]) ? 1 : 0;
    int e = e0 - a.cum[L];
    int CI = a.CI[L], CO = a.CO[L];
    int NT = CO >> 4, NCH = CI >> 5;
    int j    = e & 7;
    int lane = (e >> 3) & 63;
    int t    = (e >> 9) % NT;
    int c    = (e / (512 * NT)) % NCH;
    int k    = e / (512 * NT * NCH);
    int ci = c * 32 + (lane >> 4) * 8 + j;
    int co = t * 16 + (lane & 15);
    a.dst[L][e] = f2b(a.src[L][((long long)k * CI + ci) * CO + co]);
}

// ---------- input conv (CIN=3, f32 VALU, bf16 out) -------------------------
__global__ __launch_bounds__(256) void conv_in(
    const float* __restrict__ feat, const int* __restrict__ nbr,
    const float* __restrict__ W, short* __restrict__ out, int N) {
    __shared__ float sW[27 * 96];
    const int tid = threadIdx.x;
    for (int e = tid; e < 27 * 96; e += 256) sW[e] = W[e];
    __syncthreads();
    long long r = (long long)blockIdx.x * 256 + tid;
    if (r >= N) return;
    float acc[32];
#pragma unroll
    for (int c = 0; c < 32; c++) acc[c] = 0.f;
    for (int k = 0; k < 27; k++) {
        int idx = nbr[r * 27 + k];
        if (idx >= 0) {
            float f0 = feat[(long long)idx * 3];
            float f1 = feat[(long long)idx * 3 + 1];
            float f2 = feat[(long long)idx * 3 + 2];
            const float* w = sW + k * 96;
#pragma unroll
            for (int c = 0; c < 32; c++)
                acc[c] += f0 * w[c] + f1 * w[32 + c] + f2 * w[64 + c];
        }
    }
#pragma unroll
    for (int c = 0; c < 32; c++) out[r * 32 + c] = f2b(acc[c]);
}

// ---------- MFMA gather conv v8: phase-staged + fused stats (+opt act) -----
template<int CI1, int CI2, int COUT, int K, int G, int MT, bool FACT>
__global__ __launch_bounds__(256) void gmfma8(
    const short* __restrict__ fA, const short* __restrict__ fB,
    const int* __restrict__ nbr, const short* __restrict__ Wf,
    short* __restrict__ out, float* __restrict__ part,
    const float* __restrict__ abp, int N) {
    static_assert(K % G == 0, "G must divide K");
    static_assert(!FACT || CI2 == 0, "fused act only for single input");
    constexpr int NT  = COUT / 16;
    constexpr int NC1 = CI1 / 32;
    constexpr int NC2 = CI2 / 32;
    constexpr int NCH = (CI1 + CI2) / 32;
    constexpr int PANEL = NCH * NT * 512;
    constexpr int GSH   = G * PANEL;
    constexpr int NPH   = K / G;
    constexpr int WCH   = GSH / 4;
    constexpr int S16   = (WCH * 2) / 1024;
    constexpr int S4    = ((WCH * 2) % 1024) / 256;
    static_assert(GSH * 2 >= 2048 * NT + 1024, "scratch fits");
    __shared__ __attribute__((aligned(16))) short sB[GSH];
    const int tid  = threadIdx.x;
    const int lane = tid & 63;
    const int wid  = tid >> 6;
    const int m    = lane & 15;
    const int quad = lane >> 4;
    const long long tb0 = ((long long)blockIdx.x * 4 + wid) * (MT * 16);

    f32x4 acc[MT][NT];
#pragma unroll
    for (int mt = 0; mt < MT; mt++)
#pragma unroll
        for (int t = 0; t < NT; t++) acc[mt][t] = (f32x4)0.f;

    int idxs[MT][K];
#pragma unroll
    for (int mt = 0; mt < MT; mt++) {
        long long r = tb0 + mt * 16 + m;
        bool rv = r < N;
#pragma unroll
        for (int k = 0; k < K; k++)
            idxs[mt][k] = rv ? nbr[r * K + k] : -1;
    }

    // fused-act scale/bias preloaded to registers (channels this lane gathers)
    float aS[FACT ? NC1 * 8 : 1], aBb[FACT ? NC1 * 8 : 1];
    if constexpr (FACT) {
#pragma unroll
        for (int c = 0; c < NC1; c++)
#pragma unroll
            for (int jj = 0; jj < 8; jj++) {
                int ch = c * 32 + quad * 8 + jj;
                aS[c * 8 + jj]  = abp[ch];
                aBb[c * 8 + jj] = abp[CI1 + ch];
            }
    }

    short8 abuf[3][MT][NCH];

#define LOADA(kk, bb)                                                          \
    {                                                                          \
        _Pragma("unroll")                                                      \
        for (int _mt = 0; _mt < MT; _mt++) {                                   \
            int _i = idxs[_mt][kk];                                            \
            long long _j = _i < 0 ? 0 : _i;                                    \
            _Pragma("unroll")                                                  \
            for (int c = 0; c < NC1; c++) {                                    \
                short8 _v = *reinterpret_cast<const short8*>(                  \
                    fA + _j * CI1 + c * 32 + quad * 8);                        \
                if constexpr (FACT) {                                          \
                    short8 _o;                                                 \
                    _Pragma("unroll")                                          \
                    for (int jj = 0; jj < 8; jj++) {                           \
                        float _f = b2f(_v[jj]) * aS[c * 8 + jj] +              \
                                   aBb[c * 8 + jj];                            \
                        _o[jj] = f2b(_f > 0.f ? _f : 0.f);                     \
                    }                                                          \
                    _v = _o;                                                   \
                }                                                              \
                abuf[bb][_mt][c] = (_i >= 0) ? _v : (short8)0;                 \
            }                                                                  \
            if constexpr (NC2 > 0) {                                           \
                _Pragma("unroll")                                              \
                for (int c = 0; c < NC2; c++) {                                \
                    short8 _v = *reinterpret_cast<const short8*>(              \
                        fB + _j * CI2 + c * 32 + quad * 8);                    \
                    abuf[bb][_mt][NC1 + c] = (_i >= 0) ? _v : (short8)0;       \
                }                                                              \
            }                                                                  \
        }                                                                      \
    }
#define STAGE(ph)                                                              \
    {                                                                          \
        const short* _src = Wf + (size_t)(ph) * GSH + wid * WCH;               \
        short* _dst = &sB[wid * WCH];                                          \
        _Pragma("unroll")                                                      \
        for (int i = 0; i < S16; i++)                                          \
            __builtin_amdgcn_global_load_lds(                                  \
                (gas_short*)(_src + i * 512 + lane * 8),                       \
                (las_short*)(_dst + i * 512), 16, 0, 0);                       \
        _Pragma("unroll")                                                      \
        for (int i = 0; i < S4; i++)                                           \
            __builtin_amdgcn_global_load_lds(                                  \
                (gas_short*)(_src + S16 * 512 + i * 128 + lane * 2),           \
                (las_short*)(_dst + S16 * 512 + i * 128), 4, 0, 0);            \
    }

    STAGE(0)
    __builtin_amdgcn_sched_barrier(0);
    LOADA(0, 0)
    if constexpr (K > 1) LOADA(1, 1)
    __builtin_amdgcn_sched_barrier(0);
    asm volatile("s_waitcnt vmcnt(0)" ::: "memory");
    __builtin_amdgcn_s_barrier();
    __builtin_amdgcn_sched_barrier(0);
    asm volatile("" ::: "memory");

#pragma unroll
    for (int ph = 0; ph < NPH; ph++) {
#pragma unroll
        for (int j = 0; j < G; j++) {
            const int kg = ph * G + j;
            if (kg + 2 < K) LOADA(kg + 2, (kg + 2) % 3)
#pragma unroll
            for (int c = 0; c < NCH; c++) {
#pragma unroll
                for (int t = 0; t < NT; t++) {
                    short8 b = *reinterpret_cast<const short8*>(
                        &sB[(j * NCH * NT + c * NT + t) * 512 + lane * 8]);
#pragma unroll
                    for (int mt = 0; mt < MT; mt++)
                        acc[mt][t] = __builtin_amdgcn_mfma_f32_16x16x32_bf16(
                            abuf[kg % 3][mt][c], b, acc[mt][t], 0, 0, 0);
                }
            }
        }
        if (ph + 1 < NPH) {
            __builtin_amdgcn_sched_barrier(0);
            asm volatile("s_waitcnt lgkmcnt(0)" ::: "memory");
            __builtin_amdgcn_s_barrier();
            __builtin_amdgcn_sched_barrier(0);
            STAGE(ph + 1)
            __builtin_amdgcn_sched_barrier(0);
            asm volatile("s_waitcnt vmcnt(0)" ::: "memory");
            __builtin_amdgcn_s_barrier();
            __builtin_amdgcn_sched_barrier(0);
            asm volatile("" ::: "memory");
        }
    }
#undef LOADA
#undef STAGE
    // ---- store + fused BN stats ------------------------------------------
    float s[NT], q[NT];
#pragma unroll
    for (int t = 0; t < NT; t++) { s[t] = 0.f; q[t] = 0.f; }
#pragma unroll
    for (int mt = 0; mt < MT; mt++) {
#pragma unroll
        for (int g4 = 0; g4 < 4; g4++) {
            long long sr = tb0 + mt * 16 + quad * 4 + g4;
            if (sr < N) {
#pragma unroll
                for (int t = 0; t < NT; t++) {
                    float v = acc[mt][t][g4];
                    out[sr * COUT + t * 16 + m] = f2b(v);
                    s[t] += v; q[t] += v * v;
                }
            }
        }
    }
    __syncthreads();                 // all sB reads done; reuse as scratch
    float* ls = (float*)sB;
    float* lq = ls + 256 * NT;
#pragma unroll
    for (int t = 0; t < NT; t++) { ls[tid * NT + t] = s[t]; lq[tid * NT + t] = q[t]; }
    __syncthreads();
    if (tid < COUT) {
        int mm = tid & 15, tt = tid >> 4;
        float S = 0.f, Q = 0.f;
#pragma unroll
        for (int j2 = 0; j2 < 16; j2++) {
            S += ls[(j2 * 16 + mm) * NT + tt];
            Q += lq[(j2 * 16 + mm) * NT + tt];
        }
        part[blockIdx.x * 2 * COUT + tid]        = S;
        part[blockIdx.x * 2 * COUT + COUT + tid] = Q;
    }
}

// ---------- MFMA up conv v8: fused input act + fused stats -----------------
template<int CIN, int COUT, int G>
__global__ __launch_bounds__(256) void upmfma8(
    const short* __restrict__ f, const int* __restrict__ rb,
    const short* __restrict__ Wf, short* __restrict__ out,
    float* __restrict__ part, const float* __restrict__ abp, int N) {
    static_assert(8 % G == 0, "G must divide 8");
    constexpr int NT = COUT / 16;
    constexpr int NK = CIN / 32;
    constexpr int PANEL = NK * NT * 512;
    constexpr int GSH   = G * PANEL;
    constexpr int NPH   = 8 / G;
    constexpr int WCH   = GSH / 4;
    constexpr int S16   = (WCH * 2) / 1024;
    constexpr int S4    = ((WCH * 2) % 1024) / 256;
    static_assert(GSH * 2 >= 2048 * NT + 1024, "scratch fits");
    __shared__ __attribute__((aligned(16))) short sB[GSH];
    const int tid  = threadIdx.x;
    const int lane = tid & 63;
    const int wid  = tid >> 6;
    const int m    = lane & 15;
    const int quad = lane >> 4;
    const long long row0 = ((long long)blockIdx.x * 4 + wid) * 16;
    const long long r = row0 + m;
    const bool rv = r < N;
    const long long rc = rv ? r : 0;

    short8 af[NK];
#pragma unroll
    for (int kc = 0; kc < NK; kc++) {
        short8 v = *reinterpret_cast<const short8*>(
            f + rc * CIN + kc * 32 + quad * 8);
        short8 o;
#pragma unroll
        for (int jj = 0; jj < 8; jj++) {
            int ch = kc * 32 + quad * 8 + jj;
            float u = b2f(v[jj]) * abp[ch] + abp[CIN + ch];
            o[jj] = f2b(u > 0.f ? u : 0.f);
        }
        af[kc] = rv ? o : (short8)0;
    }
    int sidx[8][4];
#pragma unroll
    for (int g4 = 0; g4 < 4; g4++) {
        long long sr = row0 + quad * 4 + g4;
#pragma unroll
        for (int k = 0; k < 8; k++)
            sidx[k][g4] = (sr < N) ? rb[sr * 8 + k] : -1;
    }
    float s[NT], q[NT];
#pragma unroll
    for (int t = 0; t < NT; t++) { s[t] = 0.f; q[t] = 0.f; }
#define STAGE(ph)                                                              \
    {                                                                          \
        const short* _src = Wf + (size_t)(ph) * GSH + wid * WCH;               \
        short* _dst = &sB[wid * WCH];                                          \
        _Pragma("unroll")                                                      \
        for (int i = 0; i < S16; i++)                                          \
            __builtin_amdgcn_global_load_lds(                                  \
                (gas_short*)(_src + i * 512 + lane * 8),                       \
                (las_short*)(_dst + i * 512), 16, 0, 0);                       \
        _Pragma("unroll")                                                      \
        for (int i = 0; i < S4; i++)                                           \
            __builtin_amdgcn_global_load_lds(                                  \
                (gas_short*)(_src + S16 * 512 + i * 128 + lane * 2),           \
                (las_short*)(_dst + S16 * 512 + i * 128), 4, 0, 0);            \
    }
    STAGE(0)
    __builtin_amdgcn_sched_barrier(0);
    asm volatile("s_waitcnt vmcnt(0)" ::: "memory");
    __builtin_amdgcn_s_barrier();
    __builtin_amdgcn_sched_barrier(0);
    asm volatile("" ::: "memory");
#pragma unroll
    for (int ph = 0; ph < NPH; ph++) {
#pragma unroll
        for (int j = 0; j < G; j++) {
            const int k = ph * G + j;
            f32x4 acc[NT];
#pragma unroll
            for (int t = 0; t < NT; t++) acc[t] = (f32x4)0.f;
#pragma unroll
            for (int kc = 0; kc < NK; kc++) {
#pragma unroll
                for (int t = 0; t < NT; t++) {
                    short8 b = *reinterpret_cast<const short8*>(
                        &sB[(j * NK * NT + kc * NT + t) * 512 + lane * 8]);
                    acc[t] = __builtin_amdgcn_mfma_f32_16x16x32_bf16(
                        af[kc], b, acc[t], 0, 0, 0);
                }
            }
#pragma unroll
            for (int g4 = 0; g4 < 4; g4++) {
                if (sidx[k][g4] >= 0) {
#pragma unroll
                    for (int t = 0; t < NT; t++) {
                        float v = acc[t][g4];
                        out[(long long)sidx[k][g4] * COUT + t * 16 + m] = f2b(v);
                        s[t] += v; q[t] += v * v;
                    }
                }
            }
        }
        if (ph + 1 < NPH) {
            __builtin_amdgcn_sched_barrier(0);
            asm volatile("s_waitcnt lgkmcnt(0)" ::: "memory");
            __builtin_amdgcn_s_barrier();
            __builtin_amdgcn_sched_barrier(0);
            STAGE(ph + 1)
            __builtin_amdgcn_sched_barrier(0);
            asm volatile("s_waitcnt vmcnt(0)" ::: "memory");
            __builtin_amdgcn_s_barrier();
            __builtin_amdgcn_sched_barrier(0);
            asm volatile("" ::: "memory");
        }
    }
#undef STAGE
    __syncthreads();
    float* ls = (float*)sB;
    float* lq = ls + 256 * NT;
#pragma unroll
    for (int t = 0; t < NT; t++) { ls[tid * NT + t] = s[t]; lq[tid * NT + t] = q[t]; }
    __syncthreads();
    if (tid < COUT) {
        int mm = tid & 15, tt = tid >> 4;
        float S = 0.f, Q = 0.f;
#pragma unroll
        for (int j2 = 0; j2 < 16; j2++) {
            S += ls[(j2 * 16 + mm) * NT + tt];
            Q += lq[(j2 * 16 + mm) * NT + tt];
        }
        part[blockIdx.x * 2 * COUT + tid]        = S;
        part[blockIdx.x * 2 * COUT + COUT + tid] = Q;
    }
}

// ---------- BN stats (only for conv_in's output) ---------------------------
template<int C>
__global__ void bn_stats(const short* __restrict__ x, double* __restrict__ part, int N) {
    constexpr int GR  = C / 8;
    constexpr int RPB = 256 / GR;
    constexpr int ACTIVE = GR * RPB;
    __shared__ double ls[256 * 8];
    __shared__ double lq[256 * 8];
    const int tid = threadIdx.x;
    const int g   = tid % GR;
    const int rr  = tid / GR;
    double s[8], q[8];
#pragma unroll
    for (int j = 0; j < 8; j++) { s[j] = 0.0; q[j] = 0.0; }
    if (tid < ACTIVE) {
        for (long long r = (long long)blockIdx.x * RPB + rr; r < N;
             r += (long long)gridDim.x * RPB) {
            short8 v = *reinterpret_cast<const short8*>(x + r * C + g * 8);
#pragma unroll
            for (int j = 0; j < 8; j++) {
                double f = (double)b2f(v[j]);
                s[j] += f; q[j] += f * f;
            }
        }
    }
#pragma unroll
    for (int j = 0; j < 8; j++) { ls[tid * 8 + j] = s[j]; lq[tid * 8 + j] = q[j]; }
    __syncthreads();
    if (tid < C) {
        int gg = tid / 8, jj = tid % 8;
        double S = 0.0, Q = 0.0;
        for (int r2 = 0; r2 < RPB; r2++) {
            S += ls[(r2 * GR + gg) * 8 + jj];
            Q += lq[(r2 * GR + gg) * 8 + jj];
        }
        part[blockIdx.x * 256 + tid]       = S;
        part[blockIdx.x * 256 + 128 + tid] = Q;
    }
}

__global__ void bn_fin(const double* __restrict__ part, const float* __restrict__ gb,
                       int gbfull, int goff, float* __restrict__ ab,
                       int C, int P, double invN) {
    __shared__ double ss[256], sq[256];
    const int tid = threadIdx.x;
    const int c   = tid % C;
    const int g   = tid / C;
    const int G   = 256 / C;
    double s = 0.0, q = 0.0;
    if (g < G) {
        for (int p = g; p < P; p += G) {
            s += part[p * 256 + c];
            q += part[p * 256 + 128 + c];
        }
    }
    ss[tid] = s; sq[tid] = q;
    __syncthreads();
    if (tid < C) {
        for (int j = 1; j < G; j++) { s += ss[j * C + c]; q += sq[j * C + c]; }
        double mu  = s * invN;
        double var = q * invN - mu * mu;
        double a   = (double)gb[goff + c] / sqrt(var + 1e-4);
        ab[c]     = (float)a;
        ab[C + c] = (float)((double)gb[gbfull + goff + c] - mu * a);
    }
}

// ---------- bn_fin2: reduce f32 conv-epilogue partials (stride 2C) ---------
__global__ void bn_fin2(const float* __restrict__ part, const float* __restrict__ gb,
                        int gbfull, int goff, float* __restrict__ ab,
                        int C, int P, double invN) {
    __shared__ double ss[256], sq[256];
    const int tid = threadIdx.x;
    const int c   = tid % C;
    const int g   = tid / C;
    const int G   = 256 / C;
    double s = 0.0, q = 0.0;
    if (g < G) {
        for (int p = g; p < P; p += G) {
            s += (double)part[p * 2 * C + c];
            q += (double)part[p * 2 * C + C + c];
        }
    }
    ss[tid] = s; sq[tid] = q;
    __syncthreads();
    if (tid < C) {
        for (int j = 1; j < G; j++) { s += ss[j * C + c]; q += sq[j * C + c]; }
        double mu  = s * invN;
        double var = q * invN - mu * mu;
        double a   = (double)gb[goff + c] / sqrt(var + 1e-4);
        ab[c]     = (float)a;
        ab[C + c] = (float)((double)gb[gbfull + goff + c] - mu * a);
    }
}

// ---------- bnact: y = relu(x*a + b), bf16 -> bf16, 8 elems/thread ---------
template<int C>
__global__ void bnact(const short* __restrict__ x, const float* __restrict__ ab,
                      short* __restrict__ y, long long total8) {
    long long i = (long long)blockIdx.x * blockDim.x + threadIdx.x;
    if (i >= total8) return;
    long long base = i * 8;
    int c0 = (int)(base % C);
    short8 v = *reinterpret_cast<const short8*>(x + base);
    short8 o;
#pragma unroll
    for (int j = 0; j < 8; j++) {
        float f = b2f(v[j]) * ab[c0 + j] + ab[C + c0 + j];
        o[j] = f2b(f > 0.f ? f : 0.f);
    }
    *reinterpret_cast<short8*>(y + base) = o;
}

// ---------- bnact2: two tensors in one launch ------------------------------
template<int C>
__global__ void bnact2(const short* __restrict__ xa, const float* __restrict__ aba,
                       short* __restrict__ ya,
                       const short* __restrict__ xb, const float* __restrict__ abb,
                       short* __restrict__ yb, long long n8) {
    long long i = (long long)blockIdx.x * blockDim.x + threadIdx.x;
    if (i >= 2 * n8) return;
    const short* x; const float* ab; short* y; long long ii;
    if (i < n8) { x = xa; ab = aba; y = ya; ii = i; }
    else        { x = xb; ab = abb; y = yb; ii = i - n8; }
    long long base = ii * 8;
    int c0 = (int)(base % C);
    short8 v = *reinterpret_cast<const short8*>(x + base);
    short8 o;
#pragma unroll
    for (int j = 0; j < 8; j++) {
        float f = b2f(v[j]) * ab[c0 + j] + ab[C + c0 + j];
        o[j] = f2b(f > 0.f ? f : 0.f);
    }
    *reinterpret_cast<short8*>(y + base) = o;
}

// ---------- final linear (bnf fused), bf16 in, f32 out ---------------------
__global__ void final_k(const short* __restrict__ x, const float* __restrict__ ab,
                        const float* __restrict__ lw, const float* __restrict__ lb,
                        float* __restrict__ out, int N) {
    long long r = (long long)blockIdx.x * blockDim.x + threadIdx.x;
    if (r >= N) return;
    float a0 = lb[0], a1 = lb[1];
#pragma unroll
    for (int j = 0; j < 4; j++) {
        short8 v = *reinterpret_cast<const short8*>(x + r * 32 + j * 8);
#pragma unroll
        for (int t = 0; t < 8; t++) {
            int ci = 8 * j + t;
            float u = b2f(v[t]) * ab[ci] + ab[32 + ci];
            u = u > 0.f ? u : 0.f;
            a0 += u * lw[ci * 2];
            a1 += u * lw[ci * 2 + 1];
        }
    }
    out[2 * r]     = a0;
    out[2 * r + 1] = a1;
}

extern "C" void kernel_launch(void* const* d_in, const int* in_sizes, int n_in,
                              void* d_out, int out_size, void* d_ws, size_t ws_size,
                              hipStream_t stream) {
    const long long N0 = in_sizes[0] / 3;
    const long long N1 = in_sizes[26] / 8;
    const long long N2 = in_sizes[27] / 8;

    const float* feat = (const float*)d_in[0];
    const int* nbr0 = (const int*)d_in[23];
    const int* nbr1 = (const int*)d_in[24];
    const int* nbr2 = (const int*)d_in[25];
    const int* rb0  = (const int*)d_in[26];
    const int* rb1  = (const int*)d_in[27];

    // ---- arena ----
    char* p = (char*)d_ws;
    double* partd = (double*)p;
    float*  partf = (float*)p;            p += (size_t)256 * 256 * 8;   // 512 KB
    float*  ab    = (float*)p;            p += 12 * 256 * 4;
    const int wLayer[9] = {3, 5, 7, 9, 11, 13, 15, 17, 19};
    const int wK[9]  = {27, 8, 27, 8, 27, 8, 27, 8, 27};
    const int wCI[9] = {32, 32, 64, 64, 96, 96, 128, 64, 64};
    const int wCO[9] = {32, 64, 64, 96, 96, 64, 64, 32, 32};
    short* wt[9];
    WPA wpa;
    int cum = 0;
    for (int i = 0; i < 9; i++) {
        wt[i] = (short*)p;
        int n = wK[i] * wCI[i] * wCO[i];
        p += (((size_t)n * 2 + 63) & ~(size_t)63);
        wpa.src[i] = (const float*)d_in[wLayer[i]];
        wpa.dst[i] = wt[i];
        wpa.K[i] = wK[i]; wpa.CI[i] = wCI[i]; wpa.CO[i] = wCO[i];
        wpa.cum[i] = cum; cum += n;
    }
    wpa.cum[9] = cum;
    auto balloc = [&](long long elems) {
        short* q = (short*)p;
        p += (((size_t)elems * 2 + 63) & ~(size_t)63);
        return q;
    };
    short* R0 = balloc(N0 * 32);   // t0 / d0 / d1 / u1 / u0 (raw)
    short* R1 = balloc(N0 * 32);   // x0 raw (persist)
    short* R2 = balloc(N1 * 64);   // x1 raw (persist)
    short* R3 = balloc(N0 * 32);   // x2 / y1 / y0 (raw)
    short* Xb = balloc(N0 * 32);   // act out #1
    short* Yb = balloc(N0 * 32);   // act out #2

    wprep_all<<<(cum + 255) / 256, 256, 0, stream>>>(wpa, cum);

    const int gx0 = (int)((N0 + 127) / 128);
    const int gd0 = (int)((N1 + 127) / 128);
    const int gx1 = (int)((N1 + 127) / 128);
    const int gd1 = (int)((N2 + 63) / 64);
    const int gx2 = (int)((N2 + 63) / 64);
    const int gu1 = (int)((N2 + 63) / 64);
    const int gy1 = (int)((N1 + 127) / 128);
    const int gu0 = (int)((N1 + 63) / 64);
    const int gy0 = (int)((N0 + 127) / 128);

#define AB(SL) (ab + (SL) * 256)
#define FIN2(SL, GBI, GBFULL, GOFF, CH, PP, NN)                                      \
    bn_fin2<<<1, 256, 0, stream>>>(partf, (const float*)d_in[GBI], GBFULL, GOFF,     \
                                   AB(SL), CH, PP, 1.0 / (double)(NN))

    // ---- level 0 ----
    conv_in<<<(int)((N0 + 255) / 256), 256, 0, stream>>>(
        feat, nbr0, (const float*)d_in[1], R0, (int)N0);                  // t0 -> R0
    bn_stats<32><<<256, 256, 0, stream>>>(R0, partd, (int)N0);            // bn1_0
    bn_fin<<<1, 256, 0, stream>>>(partd, (const float*)d_in[2], 32, 0,
                                  AB(0), 32, 256, 1.0 / (double)N0);
    bnact<32><<<(int)((N0 * 32 / 8 + 255) / 256), 256, 0, stream>>>(
        R0, AB(0), Xb, N0 * 32 / 8);
    gmfma8<32, 0, 32, 27, 9, 2, false><<<gx0, 256, 0, stream>>>(
        Xb, nullptr, nbr0, wt[0], R1, partf, nullptr, (int)N0);           // x0 -> R1
    FIN2(1, 4, 32, 0, 32, gx0, N0);                                       // bnd_0
    FIN2(9, 18, 64, 0, 32, gx0, N0);                                      // bn2_0[x0]
    gmfma8<32, 0, 64, 8, 8, 2, true><<<gd0, 256, 0, stream>>>(
        R1, nullptr, rb0, wt[1], R0, partf, AB(1), (int)N1);              // d0 -> R0
    FIN2(2, 6, 64, 0, 64, gd0, N1);                                       // bn1_1

    // ---- level 1 ----
    bnact<64><<<(int)((N1 * 64 / 8 + 255) / 256), 256, 0, stream>>>(
        R0, AB(2), Xb, N1 * 64 / 8);
    gmfma8<64, 0, 64, 27, 9, 2, false><<<gx1, 256, 0, stream>>>(
        Xb, nullptr, nbr1, wt[2], R2, partf, nullptr, (int)N1);           // x1 -> R2
    FIN2(3, 8, 64, 0, 64, gx1, N1);                                       // bnd_1
    FIN2(6, 14, 128, 0, 64, gx1, N1);                                     // bn2_1[x1]
    gmfma8<64, 0, 96, 8, 4, 1, true><<<gd1, 256, 0, stream>>>(
        R2, nullptr, rb1, wt[3], R0, partf, AB(3), (int)N2);              // d1 -> R0
    FIN2(4, 10, 96, 0, 96, gd1, N2);                                      // bn1_2

    // ---- level 2 ----
    bnact<96><<<(int)((N2 * 96 / 8 + 255) / 256), 256, 0, stream>>>(
        R0, AB(4), Xb, N2 * 96 / 8);
    gmfma8<96, 0, 96, 27, 3, 1, false><<<gx2, 256, 0, stream>>>(
        Xb, nullptr, nbr2, wt[4], R3, partf, nullptr, (int)N2);           // x2 -> R3
    FIN2(5, 12, 96, 0, 96, gx2, N2);                                      // bnu_1

    // ---- up to level 1 ----
    upmfma8<96, 64, 4><<<gu1, 256, 0, stream>>>(
        R3, rb1, wt[5], R0, partf, AB(5), (int)N2);                       // u1 -> R0
    FIN2(7, 14, 128, 64, 64, gu1, N1);                                    // bn2_1[u1]
    bnact2<64><<<(int)((2 * (N1 * 64 / 8) + 255) / 256), 256, 0, stream>>>(
        R2, AB(6), Xb, R0, AB(7), Yb, N1 * 64 / 8);
    gmfma8<64, 64, 64, 27, 3, 2, false><<<gy1, 256, 0, stream>>>(
        Xb, Yb, nbr1, wt[6], R3, partf, nullptr, (int)N1);                // y1 -> R3
    FIN2(8, 16, 64, 0, 64, gy1, N1);                                      // bnu_0

    // ---- up to level 0 ----
    upmfma8<64, 32, 8><<<gu0, 256, 0, stream>>>(
        R3, rb0, wt[7], R0, partf, AB(8), (int)N1);                       // u0 -> R0
    FIN2(10, 18, 64, 32, 32, gu0, N0);                                    // bn2_0[u0]
    bnact2<32><<<(int)((2 * (N0 * 32 / 8) + 255) / 256), 256, 0, stream>>>(
        R1, AB(9), Xb, R0, AB(10), Yb, N0 * 32 / 8);
    gmfma8<32, 32, 32, 27, 9, 2, false><<<gy0, 256, 0, stream>>>(
        Xb, Yb, nbr0, wt[8], R3, partf, nullptr, (int)N0);                // y0 -> R3
    FIN2(11, 20, 32, 0, 32, gy0, N0);                                     // bnf

    final_k<<<(int)((N0 + 255) / 256), 256, 0, stream>>>(
        R3, AB(11), (const float*)d_in[21], (const float*)d_in[22],
        (float*)d_out, (int)N0);

#undef AB
#undef FIN2
}

// Round 6
// 896.644 us; speedup vs baseline: 1.2791x; 1.2791x over previous
//
#include <hip/hip_runtime.h>
#include <hip/hip_bf16.h>

// ---------------------------------------------------------------------------
// Sparse 3-level U-Net — Round 23: sparsity-skip convs + R19 plumbing.
// R22 post-mortem: fused-stats epilogue slowed convs (81->110us) and 1-block
// bn_fin2 over grid-sized partials serialized; reverted both.
// R23 insight: z-surface is single-valued -> ~2/3 of nbr slots are -1
// (~50% of rb slots). Per-(wave,mt) presence mask via __any -> scalar-branch
// skip of the ENTIRE k-step (gather + 16 ds_read + 16 MFMA + latency wait).
// Static 3-slot register pipeline keeps distance-2 load->MFMA. Phase-staged
// LDS (R21 structure, compiler-tracked waits). wprep_all + bnact2 kept.
// Baselines: R19 876.7us, R21 898.9us (big convs all ~80-82us).
// ---------------------------------------------------------------------------

typedef __hip_bfloat16 hbf;
typedef __attribute__((ext_vector_type(8))) short short8;
typedef __attribute__((ext_vector_type(4))) float f32x4;
typedef const __attribute__((address_space(1))) short gas_short;
typedef __attribute__((address_space(3))) short las_short;

__device__ inline float b2f(short s) {
    unsigned u = ((unsigned)(unsigned short)s) << 16;
    float f; __builtin_memcpy(&f, &u, 4); return f;
}
__device__ inline short f2b(float f) {
    hbf h = __float2bfloat16(f);
    short s; __builtin_memcpy(&s, &h, 2); return s;
}

// ---------- weight prep: all 9 layers in one launch ------------------------
struct WPA {
    const float* src[9];
    short* dst[9];
    int CI[9], CO[9];
    int cum[10];
};
__global__ __launch_bounds__(256) void wprep_all(WPA a, int total) {
    int e0 = blockIdx.x * 256 + threadIdx.x;
    if (e0 >= total) return;
    int L = 0;
#pragma unroll
    for (int i = 1; i < 9; i++) L += (e0 >= a.cum[i]) ? 1 : 0;
    int e = e0 - a.cum[L];
    int CI = a.CI[L], CO = a.CO[L];
    int NT = CO >> 4, NCH = CI >> 5;
    int j    = e & 7;
    int lane = (e >> 3) & 63;
    int t    = (e >> 9) % NT;
    int c    = (e / (512 * NT)) % NCH;
    int k    = e / (512 * NT * NCH);
    int ci = c * 32 + (lane >> 4) * 8 + j;
    int co = t * 16 + (lane & 15);
    a.dst[L][e] = f2b(a.src[L][((long long)k * CI + ci) * CO + co]);
}

// ---------- input conv (CIN=3, f32 VALU, bf16 out) -------------------------
__global__ __launch_bounds__(256) void conv_in(
    const float* __restrict__ feat, const int* __restrict__ nbr,
    const float* __restrict__ W, short* __restrict__ out, int N) {
    __shared__ float sW[27 * 96];
    const int tid = threadIdx.x;
    for (int e = tid; e < 27 * 96; e += 256) sW[e] = W[e];
    __syncthreads();
    long long r = (long long)blockIdx.x * 256 + tid;
    if (r >= N) return;
    float acc[32];
#pragma unroll
    for (int c = 0; c < 32; c++) acc[c] = 0.f;
    for (int k = 0; k < 27; k++) {
        int idx = nbr[r * 27 + k];
        if (idx >= 0) {
            float f0 = feat[(long long)idx * 3];
            float f1 = feat[(long long)idx * 3 + 1];
            float f2 = feat[(long long)idx * 3 + 2];
            const float* w = sW + k * 96;
#pragma unroll
            for (int c = 0; c < 32; c++)
                acc[c] += f0 * w[c] + f1 * w[32 + c] + f2 * w[64 + c];
        }
    }
#pragma unroll
    for (int c = 0; c < 32; c++) out[r * 32 + c] = f2b(acc[c]);
}

// ---------- MFMA gather conv v9: phase-staged + sparsity skip --------------
template<int CI1, int CI2, int COUT, int K, int G, int MT>
__global__ __launch_bounds__(256) void gmfma9(
    const short* __restrict__ fA, const short* __restrict__ fB,
    const int* __restrict__ nbr, const short* __restrict__ Wf,
    short* __restrict__ out, int N) {
    static_assert(K % G == 0, "G must divide K");
    constexpr int NT  = COUT / 16;
    constexpr int NC1 = CI1 / 32;
    constexpr int NC2 = CI2 / 32;
    constexpr int NCH = (CI1 + CI2) / 32;
    constexpr int PANEL = NCH * NT * 512;
    constexpr int GSH   = G * PANEL;
    constexpr int NPH   = K / G;
    constexpr int WCH   = GSH / 4;
    constexpr int S16   = (WCH * 2) / 1024;
    constexpr int S4    = ((WCH * 2) % 1024) / 256;
    __shared__ __attribute__((aligned(16))) short sB[GSH];
    const int tid  = threadIdx.x;
    const int lane = tid & 63;
    const int wid  = tid >> 6;
    const int m    = lane & 15;
    const int quad = lane >> 4;
    const long long tb0 = ((long long)blockIdx.x * 4 + wid) * (MT * 16);

    f32x4 acc[MT][NT];
#pragma unroll
    for (int mt = 0; mt < MT; mt++)
#pragma unroll
        for (int t = 0; t < NT; t++) acc[mt][t] = (f32x4)0.f;

#define STAGE(ph)                                                              \
    {                                                                          \
        const short* _src = Wf + (size_t)(ph) * GSH + wid * WCH;               \
        short* _dst = &sB[wid * WCH];                                          \
        _Pragma("unroll")                                                      \
        for (int i = 0; i < S16; i++)                                          \
            __builtin_amdgcn_global_load_lds(                                  \
                (gas_short*)(_src + i * 512 + lane * 8),                       \
                (las_short*)(_dst + i * 512), 16, 0, 0);                       \
        _Pragma("unroll")                                                      \
        for (int i = 0; i < S4; i++)                                           \
            __builtin_amdgcn_global_load_lds(                                  \
                (gas_short*)(_src + S16 * 512 + i * 128 + lane * 2),           \
                (las_short*)(_dst + S16 * 512 + i * 128), 4, 0, 0);            \
    }

    STAGE(0)
    __builtin_amdgcn_sched_barrier(0);

    int idxs[MT][K];
#pragma unroll
    for (int mt = 0; mt < MT; mt++) {
        long long r = tb0 + mt * 16 + m;
        bool rv = r < N;
#pragma unroll
        for (int k = 0; k < K; k++)
            idxs[mt][k] = rv ? nbr[r * K + k] : -1;
    }
    unsigned pmask[MT];
#pragma unroll
    for (int mt = 0; mt < MT; mt++) {
        unsigned pm = 0;
#pragma unroll
        for (int k = 0; k < K; k++)
            pm |= __any(idxs[mt][k] >= 0) ? (1u << k) : 0u;
        pmask[mt] = __builtin_amdgcn_readfirstlane(pm);
    }

    __builtin_amdgcn_sched_barrier(0);
    asm volatile("s_waitcnt vmcnt(0)" ::: "memory");
    __builtin_amdgcn_s_barrier();
    __builtin_amdgcn_sched_barrier(0);
    asm volatile("" ::: "memory");

    short8 S[3][NCH];   // 3-slot register pipeline (distance-2)

#define LOADS(sl, mt, kk)                                                      \
    {                                                                          \
        int _i = idxs[mt][kk];                                                 \
        long long _j = _i < 0 ? 0 : _i;                                        \
        _Pragma("unroll")                                                      \
        for (int c = 0; c < NC1; c++) {                                        \
            short8 _v = *reinterpret_cast<const short8*>(                      \
                fA + _j * CI1 + c * 32 + quad * 8);                            \
            S[sl][c] = (_i >= 0) ? _v : (short8)0;                             \
        }                                                                      \
        if constexpr (NC2 > 0) {                                               \
            _Pragma("unroll")                                                  \
            for (int c = 0; c < NC2; c++) {                                    \
                short8 _v = *reinterpret_cast<const short8*>(                  \
                    fB + _j * CI2 + c * 32 + quad * 8);                        \
                S[sl][NC1 + c] = (_i >= 0) ? _v : (short8)0;                   \
            }                                                                  \
        }                                                                      \
    }
#define MFMAS(sl, mt, jl)                                                      \
    {                                                                          \
        _Pragma("unroll")                                                      \
        for (int c = 0; c < NCH; c++) {                                        \
            _Pragma("unroll")                                                  \
            for (int t = 0; t < NT; t++) {                                     \
                short8 b = *reinterpret_cast<const short8*>(                   \
                    &sB[((jl) * NCH * NT + c * NT + t) * 512 + lane * 8]);     \
                acc[mt][t] = __builtin_amdgcn_mfma_f32_16x16x32_bf16(          \
                    S[sl][c], b, acc[mt][t], 0, 0, 0);                         \
            }                                                                  \
        }                                                                      \
    }

#pragma unroll
    for (int ph = 0; ph < NPH; ph++) {
#pragma unroll
        for (int mt = 0; mt < MT; mt++) {
            const unsigned mm = (pmask[mt] >> (ph * G)) & ((1u << G) - 1);
#pragma unroll
            for (int j = 0; j < G + 2; j++) {
                if (j < G)
                    if (mm & (1u << j)) LOADS(j % 3, mt, ph * G + j)
                if (j >= 2)
                    if (mm & (1u << (j - 2))) MFMAS((j - 2) % 3, mt, j - 2)
            }
        }
        if (ph + 1 < NPH) {
            __builtin_amdgcn_sched_barrier(0);
            asm volatile("s_waitcnt lgkmcnt(0)" ::: "memory");
            __builtin_amdgcn_s_barrier();
            __builtin_amdgcn_sched_barrier(0);
            STAGE(ph + 1)
            __builtin_amdgcn_sched_barrier(0);
            asm volatile("s_waitcnt vmcnt(0)" ::: "memory");
            __builtin_amdgcn_s_barrier();
            __builtin_amdgcn_sched_barrier(0);
            asm volatile("" ::: "memory");
        }
    }
#undef LOADS
#undef MFMAS
#undef STAGE
    // D: col = lane&15, row = quad*4 + reg
#pragma unroll
    for (int mt = 0; mt < MT; mt++) {
#pragma unroll
        for (int g4 = 0; g4 < 4; g4++) {
            long long sr = tb0 + mt * 16 + quad * 4 + g4;
            if (sr < N) {
#pragma unroll
                for (int t = 0; t < NT; t++)
                    out[sr * COUT + t * 16 + m] = f2b(acc[mt][t][g4]);
            }
        }
    }
}

// ---------- MFMA transposed (up) conv v9: phase-staged + skip --------------
template<int CIN, int COUT, int G>
__global__ __launch_bounds__(256) void upmfma9(
    const short* __restrict__ f, const int* __restrict__ rb,
    const short* __restrict__ Wf, short* __restrict__ out, int N) {
    static_assert(8 % G == 0, "G must divide 8");
    constexpr int NT = COUT / 16;
    constexpr int NK = CIN / 32;
    constexpr int PANEL = NK * NT * 512;
    constexpr int GSH   = G * PANEL;
    constexpr int NPH   = 8 / G;
    constexpr int WCH   = GSH / 4;
    constexpr int S16   = (WCH * 2) / 1024;
    constexpr int S4    = ((WCH * 2) % 1024) / 256;
    __shared__ __attribute__((aligned(16))) short sB[GSH];
    const int tid  = threadIdx.x;
    const int lane = tid & 63;
    const int wid  = tid >> 6;
    const int m    = lane & 15;
    const int quad = lane >> 4;
    const long long row0 = ((long long)blockIdx.x * 4 + wid) * 16;
    const long long r = row0 + m;
    const bool rv = r < N;
    const long long rc = rv ? r : 0;

#define STAGE(ph)                                                              \
    {                                                                          \
        const short* _src = Wf + (size_t)(ph) * GSH + wid * WCH;               \
        short* _dst = &sB[wid * WCH];                                          \
        _Pragma("unroll")                                                      \
        for (int i = 0; i < S16; i++)                                          \
            __builtin_amdgcn_global_load_lds(                                  \
                (gas_short*)(_src + i * 512 + lane * 8),                       \
                (las_short*)(_dst + i * 512), 16, 0, 0);                       \
        _Pragma("unroll")                                                      \
        for (int i = 0; i < S4; i++)                                           \
            __builtin_amdgcn_global_load_lds(                                  \
                (gas_short*)(_src + S16 * 512 + i * 128 + lane * 2),           \
                (las_short*)(_dst + S16 * 512 + i * 128), 4, 0, 0);            \
    }
    STAGE(0)
    __builtin_amdgcn_sched_barrier(0);

    short8 af[NK];
#pragma unroll
    for (int kc = 0; kc < NK; kc++) {
        short8 v = *reinterpret_cast<const short8*>(
            f + rc * CIN + kc * 32 + quad * 8);
        af[kc] = rv ? v : (short8)0;
    }
    int sidx[8][4];
#pragma unroll
    for (int g4 = 0; g4 < 4; g4++) {
        long long sr = row0 + quad * 4 + g4;
#pragma unroll
        for (int k = 0; k < 8; k++)
            sidx[k][g4] = (sr < N) ? rb[sr * 8 + k] : -1;
    }
    unsigned pm = 0;
#pragma unroll
    for (int k = 0; k < 8; k++) {
        int anyv = (sidx[k][0] >= 0) | (sidx[k][1] >= 0) |
                   (sidx[k][2] >= 0) | (sidx[k][3] >= 0);
        pm |= __any(anyv) ? (1u << k) : 0u;
    }
    pm = __builtin_amdgcn_readfirstlane(pm);

    __builtin_amdgcn_sched_barrier(0);
    asm volatile("s_waitcnt vmcnt(0)" ::: "memory");
    __builtin_amdgcn_s_barrier();
    __builtin_amdgcn_sched_barrier(0);
    asm volatile("" ::: "memory");

#pragma unroll
    for (int ph = 0; ph < NPH; ph++) {
#pragma unroll
        for (int j = 0; j < G; j++) {
            const int k = ph * G + j;
            if (pm & (1u << k)) {
                f32x4 acc[NT];
#pragma unroll
                for (int t = 0; t < NT; t++) acc[t] = (f32x4)0.f;
#pragma unroll
                for (int kc = 0; kc < NK; kc++) {
#pragma unroll
                    for (int t = 0; t < NT; t++) {
                        short8 b = *reinterpret_cast<const short8*>(
                            &sB[(j * NK * NT + kc * NT + t) * 512 + lane * 8]);
                        acc[t] = __builtin_amdgcn_mfma_f32_16x16x32_bf16(
                            af[kc], b, acc[t], 0, 0, 0);
                    }
                }
#pragma unroll
                for (int g4 = 0; g4 < 4; g4++) {
                    if (sidx[k][g4] >= 0) {
#pragma unroll
                        for (int t = 0; t < NT; t++)
                            out[(long long)sidx[k][g4] * COUT + t * 16 + m] =
                                f2b(acc[t][g4]);
                    }
                }
            }
        }
        if (ph + 1 < NPH) {
            __builtin_amdgcn_sched_barrier(0);
            asm volatile("s_waitcnt lgkmcnt(0)" ::: "memory");
            __builtin_amdgcn_s_barrier();
            __builtin_amdgcn_sched_barrier(0);
            STAGE(ph + 1)
            __builtin_amdgcn_sched_barrier(0);
            asm volatile("s_waitcnt vmcnt(0)" ::: "memory");
            __builtin_amdgcn_s_barrier();
            __builtin_amdgcn_sched_barrier(0);
            asm volatile("" ::: "memory");
        }
    }
#undef STAGE
}

// ---------- BN stats: short8 coalesced loads, f64 deterministic ------------
template<int C>
__global__ void bn_stats(const short* __restrict__ x, double* __restrict__ part, int N) {
    constexpr int GR  = C / 8;
    constexpr int RPB = 256 / GR;
    constexpr int ACTIVE = GR * RPB;
    __shared__ double ls[256 * 8];
    __shared__ double lq[256 * 8];
    const int tid = threadIdx.x;
    const int g   = tid % GR;
    const int rr  = tid / GR;
    double s[8], q[8];
#pragma unroll
    for (int j = 0; j < 8; j++) { s[j] = 0.0; q[j] = 0.0; }
    if (tid < ACTIVE) {
        for (long long r = (long long)blockIdx.x * RPB + rr; r < N;
             r += (long long)gridDim.x * RPB) {
            short8 v = *reinterpret_cast<const short8*>(x + r * C + g * 8);
#pragma unroll
            for (int j = 0; j < 8; j++) {
                double f = (double)b2f(v[j]);
                s[j] += f; q[j] += f * f;
            }
        }
    }
#pragma unroll
    for (int j = 0; j < 8; j++) { ls[tid * 8 + j] = s[j]; lq[tid * 8 + j] = q[j]; }
    __syncthreads();
    if (tid < C) {
        int gg = tid / 8, jj = tid % 8;
        double S = 0.0, Q = 0.0;
        for (int r2 = 0; r2 < RPB; r2++) {
            S += ls[(r2 * GR + gg) * 8 + jj];
            Q += lq[(r2 * GR + gg) * 8 + jj];
        }
        part[blockIdx.x * 256 + tid]       = S;
        part[blockIdx.x * 256 + 128 + tid] = Q;
    }
}

__global__ void bn_fin(const double* __restrict__ part, const float* __restrict__ gb,
                       int gbfull, int goff, float* __restrict__ ab,
                       int C, int P, double invN) {
    __shared__ double ss[256], sq[256];
    const int tid = threadIdx.x;
    const int c   = tid % C;
    const int g   = tid / C;
    const int G   = 256 / C;
    double s = 0.0, q = 0.0;
    if (g < G) {
        for (int p = g; p < P; p += G) {
            s += part[p * 256 + c];
            q += part[p * 256 + 128 + c];
        }
    }
    ss[tid] = s; sq[tid] = q;
    __syncthreads();
    if (tid < C) {
        for (int j = 1; j < G; j++) { s += ss[j * C + c]; q += sq[j * C + c]; }
        double mu  = s * invN;
        double var = q * invN - mu * mu;
        double a   = (double)gb[goff + c] / sqrt(var + 1e-4);
        ab[c]     = (float)a;
        ab[C + c] = (float)((double)gb[gbfull + goff + c] - mu * a);
    }
}

// ---------- bnact: y = relu(x*a + b), bf16 -> bf16, 8 elems/thread ---------
template<int C>
__global__ void bnact(const short* __restrict__ x, const float* __restrict__ ab,
                      short* __restrict__ y, long long total8) {
    long long i = (long long)blockIdx.x * blockDim.x + threadIdx.x;
    if (i >= total8) return;
    long long base = i * 8;
    int c0 = (int)(base % C);
    short8 v = *reinterpret_cast<const short8*>(x + base);
    short8 o;
#pragma unroll
    for (int j = 0; j < 8; j++) {
        float f = b2f(v[j]) * ab[c0 + j] + ab[C + c0 + j];
        o[j] = f2b(f > 0.f ? f : 0.f);
    }
    *reinterpret_cast<short8*>(y + base) = o;
}

// ---------- bnact2: two tensors in one launch ------------------------------
template<int C>
__global__ void bnact2(const short* __restrict__ xa, const float* __restrict__ aba,
                       short* __restrict__ ya,
                       const short* __restrict__ xb, const float* __restrict__ abb,
                       short* __restrict__ yb, long long n8) {
    long long i = (long long)blockIdx.x * blockDim.x + threadIdx.x;
    if (i >= 2 * n8) return;
    const short* x; const float* ab; short* y; long long ii;
    if (i < n8) { x = xa; ab = aba; y = ya; ii = i; }
    else        { x = xb; ab = abb; y = yb; ii = i - n8; }
    long long base = ii * 8;
    int c0 = (int)(base % C);
    short8 v = *reinterpret_cast<const short8*>(x + base);
    short8 o;
#pragma unroll
    for (int j = 0; j < 8; j++) {
        float f = b2f(v[j]) * ab[c0 + j] + ab[C + c0 + j];
        o[j] = f2b(f > 0.f ? f : 0.f);
    }
    *reinterpret_cast<short8*>(y + base) = o;
}

// ---------- final linear (bnf fused), bf16 in, f32 out ---------------------
__global__ void final_k(const short* __restrict__ x, const float* __restrict__ ab,
                        const float* __restrict__ lw, const float* __restrict__ lb,
                        float* __restrict__ out, int N) {
    long long r = (long long)blockIdx.x * blockDim.x + threadIdx.x;
    if (r >= N) return;
    float a0 = lb[0], a1 = lb[1];
#pragma unroll
    for (int j = 0; j < 4; j++) {
        short8 v = *reinterpret_cast<const short8*>(x + r * 32 + j * 8);
#pragma unroll
        for (int t = 0; t < 8; t++) {
            int ci = 8 * j + t;
            float u = b2f(v[t]) * ab[ci] + ab[32 + ci];
            u = u > 0.f ? u : 0.f;
            a0 += u * lw[ci * 2];
            a1 += u * lw[ci * 2 + 1];
        }
    }
    out[2 * r]     = a0;
    out[2 * r + 1] = a1;
}

extern "C" void kernel_launch(void* const* d_in, const int* in_sizes, int n_in,
                              void* d_out, int out_size, void* d_ws, size_t ws_size,
                              hipStream_t stream) {
    const long long N0 = in_sizes[0] / 3;
    const long long N1 = in_sizes[26] / 8;
    const long long N2 = in_sizes[27] / 8;
    const int P = 256;

    const float* feat = (const float*)d_in[0];
    const int* nbr0 = (const int*)d_in[23];
    const int* nbr1 = (const int*)d_in[24];
    const int* nbr2 = (const int*)d_in[25];
    const int* rb0  = (const int*)d_in[26];
    const int* rb1  = (const int*)d_in[27];

    // ---- arena ----
    char* p = (char*)d_ws;
    double* part = (double*)p;            p += (size_t)P * 256 * 8;     // 512 KB
    float*  ab   = (float*)p;             p += 12 * 256 * 4;
    const int wLayer[9] = {3, 5, 7, 9, 11, 13, 15, 17, 19};
    const int wK[9]  = {27, 8, 27, 8, 27, 8, 27, 8, 27};
    const int wCI[9] = {32, 32, 64, 64, 96, 96, 128, 64, 64};
    const int wCO[9] = {32, 64, 64, 96, 96, 64, 64, 32, 32};
    short* wt[9];
    WPA wpa;
    int cum = 0;
    for (int i = 0; i < 9; i++) {
        wt[i] = (short*)p;
        int n = wK[i] * wCI[i] * wCO[i];
        p += (((size_t)n * 2 + 63) & ~(size_t)63);
        wpa.src[i] = (const float*)d_in[wLayer[i]];
        wpa.dst[i] = wt[i];
        wpa.CI[i] = wCI[i]; wpa.CO[i] = wCO[i];
        wpa.cum[i] = cum; cum += n;
    }
    wpa.cum[9] = cum;
    auto balloc = [&](long long elems) {
        short* q = (short*)p;
        p += (((size_t)elems * 2 + 63) & ~(size_t)63);
        return q;
    };
    short* R0 = balloc(N0 * 32);   // t0 / d0 / d1 / u1 / u0 (raw)
    short* R1 = balloc(N0 * 32);   // x0 raw (persist)
    short* R2 = balloc(N1 * 64);   // x1 raw (persist)
    short* R3 = balloc(N0 * 32);   // x2 / y1 / y0 (raw)
    short* Xb = balloc(N0 * 32);   // act out #1
    short* Yb = balloc(N0 * 32);   // act out #2

    wprep_all<<<(cum + 255) / 256, 256, 0, stream>>>(wpa, cum);

#define STATS(CH, X, NN) bn_stats<CH><<<P, 256, 0, stream>>>(X, part, (int)(NN))
#define FIN(GBI, GBFULL, GOFF, SL, CH, NN)                                           \
    bn_fin<<<1, 256, 0, stream>>>(part, (const float*)d_in[GBI], GBFULL, GOFF,       \
                                  ab + (SL) * 256, CH, P, 1.0 / (double)(NN))
#define AB(SL) (ab + (SL) * 256)
#define ACT(CH, X, SL, Y, NN)                                                        \
    bnact<CH><<<(int)(((NN) * (CH) / 8 + 255) / 256), 256, 0, stream>>>(             \
        X, AB(SL), Y, (NN) * (CH) / 8)
#define GB1(N_) (int)(((N_) + 63) / 64)       // MT=1 blocks (64 rows)
#define GB2(N_) (int)(((N_) + 127) / 128)     // MT=2 blocks (128 rows)

    // ---- level 0 ----
    conv_in<<<(int)((N0 + 255) / 256), 256, 0, stream>>>(
        feat, nbr0, (const float*)d_in[1], R0, (int)N0);                  // t0 -> R0
    STATS(32, R0, N0); FIN(2, 32, 0, 0, 32, N0); ACT(32, R0, 0, Xb, N0);  // bn1_0
    gmfma9<32, 0, 32, 27, 9, 2><<<GB2(N0), 256, 0, stream>>>(
        Xb, nullptr, nbr0, wt[0], R1, (int)N0);                           // x0 -> R1
    STATS(32, R1, N0); FIN(4, 32, 0, 1, 32, N0); ACT(32, R1, 1, Xb, N0);  // bnd_0
    gmfma9<32, 0, 64, 8, 8, 2><<<GB2(N1), 256, 0, stream>>>(
        Xb, nullptr, rb0, wt[1], R0, (int)N1);                            // d0 -> R0

    // ---- level 1 ----
    STATS(64, R0, N1); FIN(6, 64, 0, 2, 64, N1); ACT(64, R0, 2, Xb, N1);  // bn1_1
    gmfma9<64, 0, 64, 27, 3, 2><<<GB2(N1), 256, 0, stream>>>(
        Xb, nullptr, nbr1, wt[2], R2, (int)N1);                           // x1 -> R2
    STATS(64, R2, N1); FIN(8, 64, 0, 3, 64, N1); ACT(64, R2, 3, Xb, N1);  // bnd_1
    gmfma9<64, 0, 96, 8, 2, 1><<<GB1(N2), 256, 0, stream>>>(
        Xb, nullptr, rb1, wt[3], R0, (int)N2);                            // d1 -> R0

    // ---- level 2 ----
    STATS(96, R0, N2); FIN(10, 96, 0, 4, 96, N2); ACT(96, R0, 4, Xb, N2); // bn1_2
    gmfma9<96, 0, 96, 27, 3, 1><<<GB1(N2), 256, 0, stream>>>(
        Xb, nullptr, nbr2, wt[4], R3, (int)N2);                           // x2 -> R3
    STATS(96, R3, N2); FIN(12, 96, 0, 5, 96, N2); ACT(96, R3, 5, Xb, N2); // bnu_1

    // ---- up to level 1 ----
    upmfma9<96, 64, 2><<<GB1(N2), 256, 0, stream>>>(
        Xb, rb1, wt[5], R0, (int)N2);                                     // u1 -> R0
    STATS(64, R2, N1); FIN(14, 128, 0, 6, 64, N1);                        // bn2_1 [x1]
    STATS(64, R0, N1); FIN(14, 128, 64, 7, 64, N1);                       // bn2_1 [u1]
    bnact2<64><<<(int)((2 * (N1 * 64 / 8) + 255) / 256), 256, 0, stream>>>(
        R2, AB(6), Xb, R0, AB(7), Yb, N1 * 64 / 8);
    gmfma9<64, 64, 64, 27, 3, 2><<<GB2(N1), 256, 0, stream>>>(
        Xb, Yb, nbr1, wt[6], R3, (int)N1);                                // y1 -> R3
    STATS(64, R3, N1); FIN(16, 64, 0, 8, 64, N1); ACT(64, R3, 8, Xb, N1); // bnu_0

    // ---- up to level 0 ----
    upmfma9<64, 32, 4><<<GB1(N1), 256, 0, stream>>>(
        Xb, rb0, wt[7], R0, (int)N1);                                     // u0 -> R0
    STATS(32, R1, N0); FIN(18, 64, 0, 9, 32, N0);                         // bn2_0 [x0]
    STATS(32, R0, N0); FIN(18, 64, 32, 10, 32, N0);                       // bn2_0 [u0]
    bnact2<32><<<(int)((2 * (N0 * 32 / 8) + 255) / 256), 256, 0, stream>>>(
        R1, AB(9), Xb, R0, AB(10), Yb, N0 * 32 / 8);
    gmfma9<32, 32, 32, 27, 9, 2><<<GB2(N0), 256, 0, stream>>>(
        Xb, Yb, nbr0, wt[8], R3, (int)N0);                                // y0 -> R3
    STATS(32, R3, N0); FIN(20, 32, 0, 11, 32, N0);                        // bnf

    final_k<<<(int)((N0 + 255) / 256), 256, 0, stream>>>(
        R3, AB(11), (const float*)d_in[21], (const float*)d_in[22],
        (float*)d_out, (int)N0);

#undef STATS
#undef FIN
#undef AB
#undef ACT
#undef GB1
#undef GB2
}

// Round 7
// 632.601 us; speedup vs baseline: 1.8130x; 1.4174x over previous
//
#include <hip/hip_runtime.h>
#include <hip/hip_bf16.h>

// ---------------------------------------------------------------------------
// Sparse 3-level U-Net — Round 24: lightweight fused BN stats (take 2).
// R23 lock-in: y0-class conv time (~81us) invariant to structure/occupancy/
// 40% work skip -> conv-internal levers exhausted; budget moves to plumbing.
// R22's fusion failed from (a) LDS-reduce epilogue in conv (+30% conv), (b)
// 1-block fin over grid partials. R24 fixes both:
//  - stats epilogue = 2x shfl_xor quad-reduce + banked (blockIdx&7) f32
//    atomicAdd: no barrier, no LDS, ~1us contention.
//  - bn_fin_a: 8 banks x C sums, instant.
//  - input-act fused into d0/d1/u1/u0 (single-read convs, R22-proven).
//  - conv structure = R23 gmfma9 unchanged; f64 stats only for conv_in out.
// Baseline R23: 896.6us (y0 81.4). Prediction: 680-740us.
// ---------------------------------------------------------------------------

typedef __hip_bfloat16 hbf;
typedef __attribute__((ext_vector_type(8))) short short8;
typedef __attribute__((ext_vector_type(4))) float f32x4;
typedef const __attribute__((address_space(1))) short gas_short;
typedef __attribute__((address_space(3))) short las_short;

__device__ inline float b2f(short s) {
    unsigned u = ((unsigned)(unsigned short)s) << 16;
    float f; __builtin_memcpy(&f, &u, 4); return f;
}
__device__ inline short f2b(float f) {
    hbf h = __float2bfloat16(f);
    short s; __builtin_memcpy(&s, &h, 2); return s;
}

// ---------- weight prep: all 9 layers in one launch ------------------------
struct WPA {
    const float* src[9];
    short* dst[9];
    int CI[9], CO[9];
    int cum[10];
};
__global__ __launch_bounds__(256) void wprep_all(WPA a, int total) {
    int e0 = blockIdx.x * 256 + threadIdx.x;
    if (e0 >= total) return;
    int L = 0;
#pragma unroll
    for (int i = 1; i < 9; i++) L += (e0 >= a.cum[i]) ? 1 : 0;
    int e = e0 - a.cum[L];
    int CI = a.CI[L], CO = a.CO[L];
    int NT = CO >> 4, NCH = CI >> 5;
    int j    = e & 7;
    int lane = (e >> 3) & 63;
    int t    = (e >> 9) % NT;
    int c    = (e / (512 * NT)) % NCH;
    int k    = e / (512 * NT * NCH);
    int ci = c * 32 + (lane >> 4) * 8 + j;
    int co = t * 16 + (lane & 15);
    a.dst[L][e] = f2b(a.src[L][((long long)k * CI + ci) * CO + co]);
}

// ---------- zero the atomic-stats slots ------------------------------------
__global__ void zerok(float* p, int n) {
    int i = blockIdx.x * 256 + threadIdx.x;
    if (i < n) p[i] = 0.f;
}

// ---------- input conv (CIN=3, f32 VALU, bf16 out) -------------------------
__global__ __launch_bounds__(256) void conv_in(
    const float* __restrict__ feat, const int* __restrict__ nbr,
    const float* __restrict__ W, short* __restrict__ out, int N) {
    __shared__ float sW[27 * 96];
    const int tid = threadIdx.x;
    for (int e = tid; e < 27 * 96; e += 256) sW[e] = W[e];
    __syncthreads();
    long long r = (long long)blockIdx.x * 256 + tid;
    if (r >= N) return;
    float acc[32];
#pragma unroll
    for (int c = 0; c < 32; c++) acc[c] = 0.f;
    for (int k = 0; k < 27; k++) {
        int idx = nbr[r * 27 + k];
        if (idx >= 0) {
            float f0 = feat[(long long)idx * 3];
            float f1 = feat[(long long)idx * 3 + 1];
            float f2 = feat[(long long)idx * 3 + 2];
            const float* w = sW + k * 96;
#pragma unroll
            for (int c = 0; c < 32; c++)
                acc[c] += f0 * w[c] + f1 * w[32 + c] + f2 * w[64 + c];
        }
    }
#pragma unroll
    for (int c = 0; c < 32; c++) out[r * 32 + c] = f2b(acc[c]);
}

// ---------- MFMA gather conv v10: R23 structure + light stats (+opt act) ---
template<int CI1, int CI2, int COUT, int K, int G, int MT, bool FACT>
__global__ __launch_bounds__(256) void gmfma10(
    const short* __restrict__ fA, const short* __restrict__ fB,
    const int* __restrict__ nbr, const short* __restrict__ Wf,
    short* __restrict__ out, float* __restrict__ pstat,
    const float* __restrict__ abp, int N) {
    static_assert(K % G == 0, "G must divide K");
    static_assert(!FACT || CI2 == 0, "fused act only for single input");
    constexpr int NT  = COUT / 16;
    constexpr int NC1 = CI1 / 32;
    constexpr int NC2 = CI2 / 32;
    constexpr int NCH = (CI1 + CI2) / 32;
    constexpr int PANEL = NCH * NT * 512;
    constexpr int GSH   = G * PANEL;
    constexpr int NPH   = K / G;
    constexpr int WCH   = GSH / 4;
    constexpr int S16   = (WCH * 2) / 1024;
    constexpr int S4    = ((WCH * 2) % 1024) / 256;
    __shared__ __attribute__((aligned(16))) short sB[GSH];
    const int tid  = threadIdx.x;
    const int lane = tid & 63;
    const int wid  = tid >> 6;
    const int m    = lane & 15;
    const int quad = lane >> 4;
    const long long tb0 = ((long long)blockIdx.x * 4 + wid) * (MT * 16);

    f32x4 acc[MT][NT];
#pragma unroll
    for (int mt = 0; mt < MT; mt++)
#pragma unroll
        for (int t = 0; t < NT; t++) acc[mt][t] = (f32x4)0.f;

#define STAGE(ph)                                                              \
    {                                                                          \
        const short* _src = Wf + (size_t)(ph) * GSH + wid * WCH;               \
        short* _dst = &sB[wid * WCH];                                          \
        _Pragma("unroll")                                                      \
        for (int i = 0; i < S16; i++)                                          \
            __builtin_amdgcn_global_load_lds(                                  \
                (gas_short*)(_src + i * 512 + lane * 8),                       \
                (las_short*)(_dst + i * 512), 16, 0, 0);                       \
        _Pragma("unroll")                                                      \
        for (int i = 0; i < S4; i++)                                           \
            __builtin_amdgcn_global_load_lds(                                  \
                (gas_short*)(_src + S16 * 512 + i * 128 + lane * 2),           \
                (las_short*)(_dst + S16 * 512 + i * 128), 4, 0, 0);            \
    }

    STAGE(0)
    __builtin_amdgcn_sched_barrier(0);

    int idxs[MT][K];
#pragma unroll
    for (int mt = 0; mt < MT; mt++) {
        long long r = tb0 + mt * 16 + m;
        bool rv = r < N;
#pragma unroll
        for (int k = 0; k < K; k++)
            idxs[mt][k] = rv ? nbr[r * K + k] : -1;
    }
    unsigned pmask[MT];
#pragma unroll
    for (int mt = 0; mt < MT; mt++) {
        unsigned pm = 0;
#pragma unroll
        for (int k = 0; k < K; k++)
            pm |= __any(idxs[mt][k] >= 0) ? (1u << k) : 0u;
        pmask[mt] = __builtin_amdgcn_readfirstlane(pm);
    }

    // fused-act scale/bias for gathered channels (d-convs)
    float aS[FACT ? NC1 * 8 : 1], aBb[FACT ? NC1 * 8 : 1];
    if constexpr (FACT) {
#pragma unroll
        for (int c = 0; c < NC1; c++)
#pragma unroll
            for (int jj = 0; jj < 8; jj++) {
                int ch = c * 32 + quad * 8 + jj;
                aS[c * 8 + jj]  = abp[ch];
                aBb[c * 8 + jj] = abp[CI1 + ch];
            }
    }

    __builtin_amdgcn_sched_barrier(0);
    asm volatile("s_waitcnt vmcnt(0)" ::: "memory");
    __builtin_amdgcn_s_barrier();
    __builtin_amdgcn_sched_barrier(0);
    asm volatile("" ::: "memory");

    short8 S[3][NCH];   // 3-slot register pipeline (distance-2)

#define LOADS(sl, mt, kk)                                                      \
    {                                                                          \
        int _i = idxs[mt][kk];                                                 \
        long long _j = _i < 0 ? 0 : _i;                                        \
        _Pragma("unroll")                                                      \
        for (int c = 0; c < NC1; c++) {                                        \
            short8 _v = *reinterpret_cast<const short8*>(                      \
                fA + _j * CI1 + c * 32 + quad * 8);                            \
            if constexpr (FACT) {                                              \
                short8 _o;                                                     \
                _Pragma("unroll")                                              \
                for (int jj = 0; jj < 8; jj++) {                               \
                    float _f = b2f(_v[jj]) * aS[c * 8 + jj] + aBb[c * 8 + jj]; \
                    _o[jj] = f2b(_f > 0.f ? _f : 0.f);                         \
                }                                                              \
                _v = _o;                                                       \
            }                                                                  \
            S[sl][c] = (_i >= 0) ? _v : (short8)0;                             \
        }                                                                      \
        if constexpr (NC2 > 0) {                                               \
            _Pragma("unroll")                                                  \
            for (int c = 0; c < NC2; c++) {                                    \
                short8 _v = *reinterpret_cast<const short8*>(                  \
                    fB + _j * CI2 + c * 32 + quad * 8);                        \
                S[sl][NC1 + c] = (_i >= 0) ? _v : (short8)0;                   \
            }                                                                  \
        }                                                                      \
    }
#define MFMAS(sl, mt, jl)                                                      \
    {                                                                          \
        _Pragma("unroll")                                                      \
        for (int c = 0; c < NCH; c++) {                                        \
            _Pragma("unroll")                                                  \
            for (int t = 0; t < NT; t++) {                                     \
                short8 b = *reinterpret_cast<const short8*>(                   \
                    &sB[((jl) * NCH * NT + c * NT + t) * 512 + lane * 8]);     \
                acc[mt][t] = __builtin_amdgcn_mfma_f32_16x16x32_bf16(          \
                    S[sl][c], b, acc[mt][t], 0, 0, 0);                         \
            }                                                                  \
        }                                                                      \
    }

#pragma unroll
    for (int ph = 0; ph < NPH; ph++) {
#pragma unroll
        for (int mt = 0; mt < MT; mt++) {
            const unsigned mm = (pmask[mt] >> (ph * G)) & ((1u << G) - 1);
#pragma unroll
            for (int j = 0; j < G + 2; j++) {
                if (j < G)
                    if (mm & (1u << j)) LOADS(j % 3, mt, ph * G + j)
                if (j >= 2)
                    if (mm & (1u << (j - 2))) MFMAS((j - 2) % 3, mt, j - 2)
            }
        }
        if (ph + 1 < NPH) {
            __builtin_amdgcn_sched_barrier(0);
            asm volatile("s_waitcnt lgkmcnt(0)" ::: "memory");
            __builtin_amdgcn_s_barrier();
            __builtin_amdgcn_sched_barrier(0);
            STAGE(ph + 1)
            __builtin_amdgcn_sched_barrier(0);
            asm volatile("s_waitcnt vmcnt(0)" ::: "memory");
            __builtin_amdgcn_s_barrier();
            __builtin_amdgcn_sched_barrier(0);
            asm volatile("" ::: "memory");
        }
    }
#undef LOADS
#undef MFMAS
#undef STAGE
    // ---- store + light stats: regs -> shfl quad-reduce -> banked atomics --
    float s[NT], q[NT];
#pragma unroll
    for (int t = 0; t < NT; t++) { s[t] = 0.f; q[t] = 0.f; }
#pragma unroll
    for (int mt = 0; mt < MT; mt++) {
#pragma unroll
        for (int g4 = 0; g4 < 4; g4++) {
            long long sr = tb0 + mt * 16 + quad * 4 + g4;
            if (sr < N) {
#pragma unroll
                for (int t = 0; t < NT; t++) {
                    float v = acc[mt][t][g4];
                    out[sr * COUT + t * 16 + m] = f2b(v);
                    s[t] += v; q[t] += v * v;
                }
            }
        }
    }
    float* pb = pstat + (blockIdx.x & 7) * 2 * COUT;
#pragma unroll
    for (int t = 0; t < NT; t++) {
        float sv = s[t], qv = q[t];
        sv += __shfl_xor(sv, 16); qv += __shfl_xor(qv, 16);
        sv += __shfl_xor(sv, 32); qv += __shfl_xor(qv, 32);
        if (quad == 0) {
            atomicAdd(&pb[t * 16 + m], sv);
            atomicAdd(&pb[COUT + t * 16 + m], qv);
        }
    }
}

// ---------- MFMA up conv v10: fused input act + light stats ----------------
template<int CIN, int COUT, int G>
__global__ __launch_bounds__(256) void upmfma10(
    const short* __restrict__ f, const int* __restrict__ rb,
    const short* __restrict__ Wf, short* __restrict__ out,
    float* __restrict__ pstat, const float* __restrict__ abp, int N) {
    static_assert(8 % G == 0, "G must divide 8");
    constexpr int NT = COUT / 16;
    constexpr int NK = CIN / 32;
    constexpr int PANEL = NK * NT * 512;
    constexpr int GSH   = G * PANEL;
    constexpr int NPH   = 8 / G;
    constexpr int WCH   = GSH / 4;
    constexpr int S16   = (WCH * 2) / 1024;
    constexpr int S4    = ((WCH * 2) % 1024) / 256;
    __shared__ __attribute__((aligned(16))) short sB[GSH];
    const int tid  = threadIdx.x;
    const int lane = tid & 63;
    const int wid  = tid >> 6;
    const int m    = lane & 15;
    const int quad = lane >> 4;
    const long long row0 = ((long long)blockIdx.x * 4 + wid) * 16;
    const long long r = row0 + m;
    const bool rv = r < N;
    const long long rc = rv ? r : 0;

#define STAGE(ph)                                                              \
    {                                                                          \
        const short* _src = Wf + (size_t)(ph) * GSH + wid * WCH;               \
        short* _dst = &sB[wid * WCH];                                          \
        _Pragma("unroll")                                                      \
        for (int i = 0; i < S16; i++)                                          \
            __builtin_amdgcn_global_load_lds(                                  \
                (gas_short*)(_src + i * 512 + lane * 8),                       \
                (las_short*)(_dst + i * 512), 16, 0, 0);                       \
        _Pragma("unroll")                                                      \
        for (int i = 0; i < S4; i++)                                           \
            __builtin_amdgcn_global_load_lds(                                  \
                (gas_short*)(_src + S16 * 512 + i * 128 + lane * 2),           \
                (las_short*)(_dst + S16 * 512 + i * 128), 4, 0, 0);            \
    }
    STAGE(0)
    __builtin_amdgcn_sched_barrier(0);

    short8 af[NK];
#pragma unroll
    for (int kc = 0; kc < NK; kc++) {
        short8 v = *reinterpret_cast<const short8*>(
            f + rc * CIN + kc * 32 + quad * 8);
        short8 o;
#pragma unroll
        for (int jj = 0; jj < 8; jj++) {
            int ch = kc * 32 + quad * 8 + jj;
            float u = b2f(v[jj]) * abp[ch] + abp[CIN + ch];
            o[jj] = f2b(u > 0.f ? u : 0.f);
        }
        af[kc] = rv ? o : (short8)0;
    }
    int sidx[8][4];
#pragma unroll
    for (int g4 = 0; g4 < 4; g4++) {
        long long sr = row0 + quad * 4 + g4;
#pragma unroll
        for (int k = 0; k < 8; k++)
            sidx[k][g4] = (sr < N) ? rb[sr * 8 + k] : -1;
    }
    unsigned pm = 0;
#pragma unroll
    for (int k = 0; k < 8; k++) {
        int anyv = (sidx[k][0] >= 0) | (sidx[k][1] >= 0) |
                   (sidx[k][2] >= 0) | (sidx[k][3] >= 0);
        pm |= __any(anyv) ? (1u << k) : 0u;
    }
    pm = __builtin_amdgcn_readfirstlane(pm);

    float s[NT], q[NT];
#pragma unroll
    for (int t = 0; t < NT; t++) { s[t] = 0.f; q[t] = 0.f; }

    __builtin_amdgcn_sched_barrier(0);
    asm volatile("s_waitcnt vmcnt(0)" ::: "memory");
    __builtin_amdgcn_s_barrier();
    __builtin_amdgcn_sched_barrier(0);
    asm volatile("" ::: "memory");

#pragma unroll
    for (int ph = 0; ph < NPH; ph++) {
#pragma unroll
        for (int j = 0; j < G; j++) {
            const int k = ph * G + j;
            if (pm & (1u << k)) {
                f32x4 acc[NT];
#pragma unroll
                for (int t = 0; t < NT; t++) acc[t] = (f32x4)0.f;
#pragma unroll
                for (int kc = 0; kc < NK; kc++) {
#pragma unroll
                    for (int t = 0; t < NT; t++) {
                        short8 b = *reinterpret_cast<const short8*>(
                            &sB[(j * NK * NT + kc * NT + t) * 512 + lane * 8]);
                        acc[t] = __builtin_amdgcn_mfma_f32_16x16x32_bf16(
                            af[kc], b, acc[t], 0, 0, 0);
                    }
                }
#pragma unroll
                for (int g4 = 0; g4 < 4; g4++) {
                    if (sidx[k][g4] >= 0) {
#pragma unroll
                        for (int t = 0; t < NT; t++) {
                            float v = acc[t][g4];
                            out[(long long)sidx[k][g4] * COUT + t * 16 + m] =
                                f2b(v);
                            s[t] += v; q[t] += v * v;
                        }
                    }
                }
            }
        }
        if (ph + 1 < NPH) {
            __builtin_amdgcn_sched_barrier(0);
            asm volatile("s_waitcnt lgkmcnt(0)" ::: "memory");
            __builtin_amdgcn_s_barrier();
            __builtin_amdgcn_sched_barrier(0);
            STAGE(ph + 1)
            __builtin_amdgcn_sched_barrier(0);
            asm volatile("s_waitcnt vmcnt(0)" ::: "memory");
            __builtin_amdgcn_s_barrier();
            __builtin_amdgcn_sched_barrier(0);
            asm volatile("" ::: "memory");
        }
    }
#undef STAGE
    float* pb = pstat + (blockIdx.x & 7) * 2 * COUT;
#pragma unroll
    for (int t = 0; t < NT; t++) {
        float sv = s[t], qv = q[t];
        sv += __shfl_xor(sv, 16); qv += __shfl_xor(qv, 16);
        sv += __shfl_xor(sv, 32); qv += __shfl_xor(qv, 32);
        if (quad == 0) {
            atomicAdd(&pb[t * 16 + m], sv);
            atomicAdd(&pb[COUT + t * 16 + m], qv);
        }
    }
}

// ---------- BN stats (only for conv_in's output), f64 deterministic --------
template<int C>
__global__ void bn_stats(const short* __restrict__ x, double* __restrict__ part, int N) {
    constexpr int GR  = C / 8;
    constexpr int RPB = 256 / GR;
    constexpr int ACTIVE = GR * RPB;
    __shared__ double ls[256 * 8];
    __shared__ double lq[256 * 8];
    const int tid = threadIdx.x;
    const int g   = tid % GR;
    const int rr  = tid / GR;
    double s[8], q[8];
#pragma unroll
    for (int j = 0; j < 8; j++) { s[j] = 0.0; q[j] = 0.0; }
    if (tid < ACTIVE) {
        for (long long r = (long long)blockIdx.x * RPB + rr; r < N;
             r += (long long)gridDim.x * RPB) {
            short8 v = *reinterpret_cast<const short8*>(x + r * C + g * 8);
#pragma unroll
            for (int j = 0; j < 8; j++) {
                double f = (double)b2f(v[j]);
                s[j] += f; q[j] += f * f;
            }
        }
    }
#pragma unroll
    for (int j = 0; j < 8; j++) { ls[tid * 8 + j] = s[j]; lq[tid * 8 + j] = q[j]; }
    __syncthreads();
    if (tid < C) {
        int gg = tid / 8, jj = tid % 8;
        double S = 0.0, Q = 0.0;
        for (int r2 = 0; r2 < RPB; r2++) {
            S += ls[(r2 * GR + gg) * 8 + jj];
            Q += lq[(r2 * GR + gg) * 8 + jj];
        }
        part[blockIdx.x * 256 + tid]       = S;
        part[blockIdx.x * 256 + 128 + tid] = Q;
    }
}

__global__ void bn_fin(const double* __restrict__ part, const float* __restrict__ gb,
                       int gbfull, int goff, float* __restrict__ ab,
                       int C, int P, double invN) {
    __shared__ double ss[256], sq[256];
    const int tid = threadIdx.x;
    const int c   = tid % C;
    const int g   = tid / C;
    const int G   = 256 / C;
    double s = 0.0, q = 0.0;
    if (g < G) {
        for (int p = g; p < P; p += G) {
            s += part[p * 256 + c];
            q += part[p * 256 + 128 + c];
        }
    }
    ss[tid] = s; sq[tid] = q;
    __syncthreads();
    if (tid < C) {
        for (int j = 1; j < G; j++) { s += ss[j * C + c]; q += sq[j * C + c]; }
        double mu  = s * invN;
        double var = q * invN - mu * mu;
        double a   = (double)gb[goff + c] / sqrt(var + 1e-4);
        ab[c]     = (float)a;
        ab[C + c] = (float)((double)gb[gbfull + goff + c] - mu * a);
    }
}

// ---------- bn_fin_a: reduce 8 atomic banks -> ab --------------------------
__global__ void bn_fin_a(const float* __restrict__ pst, const float* __restrict__ gb,
                         int gbfull, int goff, float* __restrict__ ab,
                         int C, double invN) {
    int c = threadIdx.x;
    if (c >= C) return;
    double s = 0.0, q = 0.0;
#pragma unroll
    for (int b = 0; b < 8; b++) {
        s += (double)pst[b * 2 * C + c];
        q += (double)pst[b * 2 * C + C + c];
    }
    double mu  = s * invN;
    double var = q * invN - mu * mu;
    double a   = (double)gb[goff + c] / sqrt(var + 1e-4);
    ab[c]     = (float)a;
    ab[C + c] = (float)((double)gb[gbfull + goff + c] - mu * a);
}

// ---------- bnact: y = relu(x*a + b), bf16 -> bf16, 8 elems/thread ---------
template<int C>
__global__ void bnact(const short* __restrict__ x, const float* __restrict__ ab,
                      short* __restrict__ y, long long total8) {
    long long i = (long long)blockIdx.x * blockDim.x + threadIdx.x;
    if (i >= total8) return;
    long long base = i * 8;
    int c0 = (int)(base % C);
    short8 v = *reinterpret_cast<const short8*>(x + base);
    short8 o;
#pragma unroll
    for (int j = 0; j < 8; j++) {
        float f = b2f(v[j]) * ab[c0 + j] + ab[C + c0 + j];
        o[j] = f2b(f > 0.f ? f : 0.f);
    }
    *reinterpret_cast<short8*>(y + base) = o;
}

// ---------- bnact2: two tensors in one launch ------------------------------
template<int C>
__global__ void bnact2(const short* __restrict__ xa, const float* __restrict__ aba,
                       short* __restrict__ ya,
                       const short* __restrict__ xb, const float* __restrict__ abb,
                       short* __restrict__ yb, long long n8) {
    long long i = (long long)blockIdx.x * blockDim.x + threadIdx.x;
    if (i >= 2 * n8) return;
    const short* x; const float* ab; short* y; long long ii;
    if (i < n8) { x = xa; ab = aba; y = ya; ii = i; }
    else        { x = xb; ab = abb; y = yb; ii = i - n8; }
    long long base = ii * 8;
    int c0 = (int)(base % C);
    short8 v = *reinterpret_cast<const short8*>(x + base);
    short8 o;
#pragma unroll
    for (int j = 0; j < 8; j++) {
        float f = b2f(v[j]) * ab[c0 + j] + ab[C + c0 + j];
        o[j] = f2b(f > 0.f ? f : 0.f);
    }
    *reinterpret_cast<short8*>(y + base) = o;
}

// ---------- final linear (bnf fused), bf16 in, f32 out ---------------------
__global__ void final_k(const short* __restrict__ x, const float* __restrict__ ab,
                        const float* __restrict__ lw, const float* __restrict__ lb,
                        float* __restrict__ out, int N) {
    long long r = (long long)blockIdx.x * blockDim.x + threadIdx.x;
    if (r >= N) return;
    float a0 = lb[0], a1 = lb[1];
#pragma unroll
    for (int j = 0; j < 4; j++) {
        short8 v = *reinterpret_cast<const short8*>(x + r * 32 + j * 8);
#pragma unroll
        for (int t = 0; t < 8; t++) {
            int ci = 8 * j + t;
            float u = b2f(v[t]) * ab[ci] + ab[32 + ci];
            u = u > 0.f ? u : 0.f;
            a0 += u * lw[ci * 2];
            a1 += u * lw[ci * 2 + 1];
        }
    }
    out[2 * r]     = a0;
    out[2 * r + 1] = a1;
}

extern "C" void kernel_launch(void* const* d_in, const int* in_sizes, int n_in,
                              void* d_out, int out_size, void* d_ws, size_t ws_size,
                              hipStream_t stream) {
    const long long N0 = in_sizes[0] / 3;
    const long long N1 = in_sizes[26] / 8;
    const long long N2 = in_sizes[27] / 8;
    const int P = 256;

    const float* feat = (const float*)d_in[0];
    const int* nbr0 = (const int*)d_in[23];
    const int* nbr1 = (const int*)d_in[24];
    const int* nbr2 = (const int*)d_in[25];
    const int* rb0  = (const int*)d_in[26];
    const int* rb1  = (const int*)d_in[27];

    // ---- arena ----
    char* p = (char*)d_ws;
    double* part = (double*)p;            p += (size_t)P * 256 * 8;     // 512 KB
    float*  ab   = (float*)p;             p += 12 * 256 * 4;
    float*  pst  = (float*)p;             p += (size_t)10 * 2048 * 4;   // 10 slots x 8 banks x 2*128
    const int wLayer[9] = {3, 5, 7, 9, 11, 13, 15, 17, 19};
    const int wK[9]  = {27, 8, 27, 8, 27, 8, 27, 8, 27};
    const int wCI[9] = {32, 32, 64, 64, 96, 96, 128, 64, 64};
    const int wCO[9] = {32, 64, 64, 96, 96, 64, 64, 32, 32};
    short* wt[9];
    WPA wpa;
    int cum = 0;
    for (int i = 0; i < 9; i++) {
        wt[i] = (short*)p;
        int n = wK[i] * wCI[i] * wCO[i];
        p += (((size_t)n * 2 + 63) & ~(size_t)63);
        wpa.src[i] = (const float*)d_in[wLayer[i]];
        wpa.dst[i] = wt[i];
        wpa.CI[i] = wCI[i]; wpa.CO[i] = wCO[i];
        wpa.cum[i] = cum; cum += n;
    }
    wpa.cum[9] = cum;
    auto balloc = [&](long long elems) {
        short* q = (short*)p;
        p += (((size_t)elems * 2 + 63) & ~(size_t)63);
        return q;
    };
    short* R0 = balloc(N0 * 32);   // t0 / d0 / d1 / u1 / u0 (raw)
    short* R1 = balloc(N0 * 32);   // x0 raw (persist)
    short* R2 = balloc(N1 * 64);   // x1 raw (persist)
    short* R3 = balloc(N0 * 32);   // x2 / y1 / y0 (raw)
    short* Xb = balloc(N0 * 32);   // act out #1
    short* Yb = balloc(N0 * 32);   // act out #2

    wprep_all<<<(cum + 255) / 256, 256, 0, stream>>>(wpa, cum);
    zerok<<<(10 * 2048 + 255) / 256, 256, 0, stream>>>(pst, 10 * 2048);

#define AB(SL) (ab + (SL) * 256)
#define PS(SL) (pst + (SL) * 2048)
#define FINA(PSL, GBI, GBFULL, GOFF, SL, CH, NN)                                     \
    bn_fin_a<<<1, 128, 0, stream>>>(PS(PSL), (const float*)d_in[GBI], GBFULL, GOFF,  \
                                    AB(SL), CH, 1.0 / (double)(NN))
#define GB1(N_) (int)(((N_) + 63) / 64)       // MT=1 blocks (64 rows)
#define GB2(N_) (int)(((N_) + 127) / 128)     // MT=2 blocks (128 rows)

    // ---- level 0 ----
    conv_in<<<(int)((N0 + 255) / 256), 256, 0, stream>>>(
        feat, nbr0, (const float*)d_in[1], R0, (int)N0);                  // t0 -> R0
    bn_stats<32><<<P, 256, 0, stream>>>(R0, part, (int)N0);               // bn1_0
    bn_fin<<<1, 256, 0, stream>>>(part, (const float*)d_in[2], 32, 0,
                                  AB(0), 32, P, 1.0 / (double)N0);
    bnact<32><<<(int)((N0 * 32 / 8 + 255) / 256), 256, 0, stream>>>(
        R0, AB(0), Xb, N0 * 32 / 8);
    gmfma10<32, 0, 32, 27, 9, 2, false><<<GB2(N0), 256, 0, stream>>>(
        Xb, nullptr, nbr0, wt[0], R1, PS(0), nullptr, (int)N0);           // x0 -> R1
    FINA(0, 4, 32, 0, 1, 32, N0);                                         // bnd_0
    FINA(0, 18, 64, 0, 9, 32, N0);                                        // bn2_0[x0]
    gmfma10<32, 0, 64, 8, 8, 2, true><<<GB2(N1), 256, 0, stream>>>(
        R1, nullptr, rb0, wt[1], R0, PS(1), AB(1), (int)N1);              // d0 -> R0
    FINA(1, 6, 64, 0, 2, 64, N1);                                         // bn1_1

    // ---- level 1 ----
    bnact<64><<<(int)((N1 * 64 / 8 + 255) / 256), 256, 0, stream>>>(
        R0, AB(2), Xb, N1 * 64 / 8);
    gmfma10<64, 0, 64, 27, 3, 2, false><<<GB2(N1), 256, 0, stream>>>(
        Xb, nullptr, nbr1, wt[2], R2, PS(2), nullptr, (int)N1);           // x1 -> R2
    FINA(2, 8, 64, 0, 3, 64, N1);                                         // bnd_1
    FINA(2, 14, 128, 0, 6, 64, N1);                                       // bn2_1[x1]
    gmfma10<64, 0, 96, 8, 2, 1, true><<<GB1(N2), 256, 0, stream>>>(
        R2, nullptr, rb1, wt[3], R0, PS(3), AB(3), (int)N2);              // d1 -> R0
    FINA(3, 10, 96, 0, 4, 96, N2);                                        // bn1_2

    // ---- level 2 ----
    bnact<96><<<(int)((N2 * 96 / 8 + 255) / 256), 256, 0, stream>>>(
        R0, AB(4), Xb, N2 * 96 / 8);
    gmfma10<96, 0, 96, 27, 3, 1, false><<<GB1(N2), 256, 0, stream>>>(
        Xb, nullptr, nbr2, wt[4], R3, PS(4), nullptr, (int)N2);           // x2 -> R3
    FINA(4, 12, 96, 0, 5, 96, N2);                                        // bnu_1

    // ---- up to level 1 ----
    upmfma10<96, 64, 2><<<GB1(N2), 256, 0, stream>>>(
        R3, rb1, wt[5], R0, PS(5), AB(5), (int)N2);                       // u1 -> R0
    FINA(5, 14, 128, 64, 7, 64, N1);                                      // bn2_1[u1]
    bnact2<64><<<(int)((2 * (N1 * 64 / 8) + 255) / 256), 256, 0, stream>>>(
        R2, AB(6), Xb, R0, AB(7), Yb, N1 * 64 / 8);
    gmfma10<64, 64, 64, 27, 3, 2, false><<<GB2(N1), 256, 0, stream>>>(
        Xb, Yb, nbr1, wt[6], R3, PS(6), nullptr, (int)N1);                // y1 -> R3
    FINA(6, 16, 64, 0, 8, 64, N1);                                        // bnu_0

    // ---- up to level 0 ----
    upmfma10<64, 32, 4><<<GB1(N1), 256, 0, stream>>>(
        R3, rb0, wt[7], R0, PS(7), AB(8), (int)N1);                       // u0 -> R0
    FINA(7, 18, 64, 32, 10, 32, N0);                                      // bn2_0[u0]
    bnact2<32><<<(int)((2 * (N0 * 32 / 8) + 255) / 256), 256, 0, stream>>>(
        R1, AB(9), Xb, R0, AB(10), Yb, N0 * 32 / 8);
    gmfma10<32, 32, 32, 27, 9, 2, false><<<GB2(N0), 256, 0, stream>>>(
        Xb, Yb, nbr0, wt[8], R3, PS(8), nullptr, (int)N0);                // y0 -> R3
    FINA(8, 20, 32, 0, 11, 32, N0);                                       // bnf

    final_k<<<(int)((N0 + 255) / 256), 256, 0, stream>>>(
        R3, AB(11), (const float*)d_in[21], (const float*)d_in[22],
        (float*)d_out, (int)N0);

#undef AB
#undef PS
#undef FINA
#undef GB1
#undef GB2
}

// Round 9
// 565.990 us; speedup vs baseline: 2.0263x; 1.1177x over previous
//
#include <hip/hip_runtime.h>
#include <hip/hip_bf16.h>

// ---------------------------------------------------------------------------
// Sparse 3-level U-Net — Round 25 (resubmit; R8 was an infra failure).
// R24 (633us): BN plumbing fused (banked atomics) — kept. Top cost now the
// N0-level K=27 convs (x0,y0 ~83us, all pipes idle = gather-latency).
// R25 insight: level-0 rows are meshgrid-ordered (r = x*512+y, argsort =
// identity) -> nbr0 is a regular 3x3 spatial stencil; only dz-presence is
// data-dependent. stencil0: LDS-stage 3 x-strips x 130 rows (act fused at
// stage, XOR-swizzled), 9 spatial steps x 3 dz slots, per-lane cndmask by
// 27-bit presence mask (prepped once from nbr0), B-frags direct from L2.
// One barrier, no manual waitcnts. Eliminates bnact<32>, bnact2<32>.
// Baseline R24: 632.6us (y0 83.5). Prediction: 510-550us.
// ---------------------------------------------------------------------------

typedef __hip_bfloat16 hbf;
typedef __attribute__((ext_vector_type(8))) short short8;
typedef __attribute__((ext_vector_type(4))) float f32x4;
typedef const __attribute__((address_space(1))) short gas_short;
typedef __attribute__((address_space(3))) short las_short;

__device__ inline float b2f(short s) {
    unsigned u = ((unsigned)(unsigned short)s) << 16;
    float f; __builtin_memcpy(&f, &u, 4); return f;
}
__device__ inline short f2b(float f) {
    hbf h = __float2bfloat16(f);
    short s; __builtin_memcpy(&s, &h, 2); return s;
}

// ---------- weight prep: all 9 layers in one launch ------------------------
struct WPA {
    const float* src[9];
    short* dst[9];
    int CI[9], CO[9];
    int cum[10];
};
__global__ __launch_bounds__(256) void wprep_all(WPA a, int total) {
    int e0 = blockIdx.x * 256 + threadIdx.x;
    if (e0 >= total) return;
    int L = 0;
#pragma unroll
    for (int i = 1; i < 9; i++) L += (e0 >= a.cum[i]) ? 1 : 0;
    int e = e0 - a.cum[L];
    int CI = a.CI[L], CO = a.CO[L];
    int NT = CO >> 4, NCH = CI >> 5;
    int j    = e & 7;
    int lane = (e >> 3) & 63;
    int t    = (e >> 9) % NT;
    int c    = (e / (512 * NT)) % NCH;
    int k    = e / (512 * NT * NCH);
    int ci = c * 32 + (lane >> 4) * 8 + j;
    int co = t * 16 + (lane & 15);
    a.dst[L][e] = f2b(a.src[L][((long long)k * CI + ci) * CO + co]);
}

// ---------- zero the atomic-stats slots ------------------------------------
__global__ void zerok(float* p, int n) {
    int i = blockIdx.x * 256 + threadIdx.x;
    if (i < n) p[i] = 0.f;
}

// ---------- presence mask from nbr0 (27 bits/row) --------------------------
__global__ __launch_bounds__(256) void nbrmask_k(const int* __restrict__ nbr,
                                                 unsigned* __restrict__ msk, int N) {
    long long r = (long long)blockIdx.x * 256 + threadIdx.x;
    if (r >= N) return;
    unsigned mv = 0;
#pragma unroll
    for (int k = 0; k < 27; k++)
        mv |= (nbr[r * 27 + k] >= 0) ? (1u << k) : 0u;
    msk[r] = mv;
}

// ---------- input conv (CIN=3, f32 VALU, bf16 out) -------------------------
__global__ __launch_bounds__(256) void conv_in(
    const float* __restrict__ feat, const int* __restrict__ nbr,
    const float* __restrict__ W, short* __restrict__ out, int N) {
    __shared__ float sW[27 * 96];
    const int tid = threadIdx.x;
    for (int e = tid; e < 27 * 96; e += 256) sW[e] = W[e];
    __syncthreads();
    long long r = (long long)blockIdx.x * 256 + tid;
    if (r >= N) return;
    float acc[32];
#pragma unroll
    for (int c = 0; c < 32; c++) acc[c] = 0.f;
    for (int k = 0; k < 27; k++) {
        int idx = nbr[r * 27 + k];
        if (idx >= 0) {
            float f0 = feat[(long long)idx * 3];
            float f1 = feat[(long long)idx * 3 + 1];
            float f2 = feat[(long long)idx * 3 + 2];
            const float* w = sW + k * 96;
#pragma unroll
            for (int c = 0; c < 32; c++)
                acc[c] += f0 * w[c] + f1 * w[32 + c] + f2 * w[64 + c];
        }
    }
#pragma unroll
    for (int c = 0; c < 32; c++) out[r * 32 + c] = f2b(acc[c]);
}

// ---------- stencil conv for level 0 (dense 512x512 grid) ------------------
// Block = 128 consecutive rows (one x, y in [ystart, ystart+128)).
// LDS: 3 x-strips x 130 rows x CIT ch, act applied at stage, XOR-swizzled.
template<int CI1, int CI2, int COUT>
__global__ __launch_bounds__(256) void stencil0(
    const short* __restrict__ fA, const short* __restrict__ fB,
    const unsigned* __restrict__ msk, const short* __restrict__ Wf,
    short* __restrict__ out, float* __restrict__ pstat,
    const float* __restrict__ abA, const float* __restrict__ abB, int N) {
    constexpr int CIT  = CI1 + CI2;
    constexpr int NCH  = CIT / 32;
    constexpr int NT   = COUT / 16;
    constexpr int MT   = 2;
    constexpr int CIB  = CIT * 2;               // bytes per row
    constexpr int ROWS = 130;
    constexpr int NC8  = CIT / 8;               // 16B chunks per row
    constexpr int SWB  = (CIB >= 128) ? 7 : 3;  // swizzle row bits
    __shared__ __attribute__((aligned(16))) char sA[3 * ROWS * CIB];
    const int tid  = threadIdx.x;
    const int lane = tid & 63;
    const int wid  = tid >> 6;
    const int m    = lane & 15;
    const int quad = lane >> 4;
    const int bid  = blockIdx.x;
    const int xq     = bid >> 2;                // x line (512 y / 128 = 4)
    const int ystart = (bid & 3) << 7;
    const long long R = (long long)bid * 128;

    // ---- stage with fused act (each thread owns one fixed 8-ch chunk) ----
    {
        const int c8 = tid % NC8;
        const bool isA = (c8 * 8) < CI1;
        const short* src  = isA ? fA : fB;
        const float* abp  = isA ? abA : abB;
        const int   srcCI = isA ? CI1 : CI2;
        const int   chb   = isA ? c8 * 8 : c8 * 8 - CI1;
        float s_[8], b_[8];
#pragma unroll
        for (int jj = 0; jj < 8; jj++) {
            s_[jj] = abp[chb + jj];
            b_[jj] = abp[srcCI + chb + jj];
        }
        for (int e = tid; e < 3 * ROWS * NC8; e += 256) {
            int rr = (e / NC8) % ROWS;
            int st = e / (NC8 * ROWS);
            long long gr = (long long)(xq - 1 + st) * 512 + (ystart - 1 + rr);
            long long grc = (gr < 0 || gr >= N) ? 0 : gr;   // fault-safe; masked later
            short8 v = *reinterpret_cast<const short8*>(src + grc * srcCI + chb);
            short8 o;
#pragma unroll
            for (int jj = 0; jj < 8; jj++) {
                float f = b2f(v[jj]) * s_[jj] + b_[jj];
                o[jj] = f2b(f > 0.f ? f : 0.f);
            }
            int byte = (st * ROWS + rr) * CIB + c8 * 16;
            byte ^= ((rr & SWB) << 4);
            *reinterpret_cast<short8*>(sA + byte) = o;
        }
    }
    __syncthreads();

    f32x4 acc[MT][NT];
#pragma unroll
    for (int mt = 0; mt < MT; mt++)
#pragma unroll
        for (int t = 0; t < NT; t++) acc[mt][t] = (f32x4)0.f;

    unsigned mv[MT];
#pragma unroll
    for (int mt = 0; mt < MT; mt++) {
        long long r = R + wid * 32 + mt * 16 + m;
        mv[mt] = (r < N) ? msk[r] : 0u;
    }

#pragma unroll
    for (int s9 = 0; s9 < 9; s9++) {
        const int st = s9 / 3;          // strip index = dx+1
        const int dy = s9 % 3 - 1;
        short8 a[MT][NCH];
#pragma unroll
        for (int mt = 0; mt < MT; mt++) {
            int rl = 1 + wid * 32 + mt * 16 + m + dy;
#pragma unroll
            for (int c = 0; c < NCH; c++) {
                int byte = (st * ROWS + rl) * CIB + (c * 4 + quad) * 16;
                byte ^= ((rl & SWB) << 4);
                a[mt][c] = *reinterpret_cast<const short8*>(sA + byte);
            }
        }
#pragma unroll
        for (int z3 = 0; z3 < 3; z3++) {
            const int k = s9 * 3 + z3;
            unsigned anyb = (mv[0] >> k) & 1;
            if (MT > 1) anyb |= (mv[1] >> k) & 1;
            if (__any(anyb)) {
                short8 bf[NCH][NT];
#pragma unroll
                for (int c = 0; c < NCH; c++)
#pragma unroll
                    for (int t = 0; t < NT; t++)
                        bf[c][t] = *reinterpret_cast<const short8*>(
                            Wf + ((size_t)(k * NCH + c) * NT + t) * 512 + lane * 8);
#pragma unroll
                for (int mt = 0; mt < MT; mt++) {
                    const bool bb = (mv[mt] >> k) & 1;
                    short8 asel[NCH];
#pragma unroll
                    for (int c = 0; c < NCH; c++)
                        asel[c] = bb ? a[mt][c] : (short8)0;
#pragma unroll
                    for (int c = 0; c < NCH; c++)
#pragma unroll
                        for (int t = 0; t < NT; t++)
                            acc[mt][t] = __builtin_amdgcn_mfma_f32_16x16x32_bf16(
                                asel[c], bf[c][t], acc[mt][t], 0, 0, 0);
                }
            }
        }
    }

    // ---- store + light stats: shfl quad-reduce -> banked atomics ----------
    float s[NT], q[NT];
#pragma unroll
    for (int t = 0; t < NT; t++) { s[t] = 0.f; q[t] = 0.f; }
#pragma unroll
    for (int mt = 0; mt < MT; mt++) {
#pragma unroll
        for (int g4 = 0; g4 < 4; g4++) {
            long long sr = R + wid * 32 + mt * 16 + quad * 4 + g4;
            if (sr < N) {
#pragma unroll
                for (int t = 0; t < NT; t++) {
                    float v = acc[mt][t][g4];
                    out[sr * COUT + t * 16 + m] = f2b(v);
                    s[t] += v; q[t] += v * v;
                }
            }
        }
    }
    float* pb = pstat + (blockIdx.x & 7) * 2 * COUT;
#pragma unroll
    for (int t = 0; t < NT; t++) {
        float sv = s[t], qv = q[t];
        sv += __shfl_xor(sv, 16); qv += __shfl_xor(qv, 16);
        sv += __shfl_xor(sv, 32); qv += __shfl_xor(qv, 32);
        if (quad == 0) {
            atomicAdd(&pb[t * 16 + m], sv);
            atomicAdd(&pb[COUT + t * 16 + m], qv);
        }
    }
}

// ---------- MFMA gather conv v10 (R24, unchanged) --------------------------
template<int CI1, int CI2, int COUT, int K, int G, int MT, bool FACT>
__global__ __launch_bounds__(256) void gmfma10(
    const short* __restrict__ fA, const short* __restrict__ fB,
    const int* __restrict__ nbr, const short* __restrict__ Wf,
    short* __restrict__ out, float* __restrict__ pstat,
    const float* __restrict__ abp, int N) {
    static_assert(K % G == 0, "G must divide K");
    static_assert(!FACT || CI2 == 0, "fused act only for single input");
    constexpr int NT  = COUT / 16;
    constexpr int NC1 = CI1 / 32;
    constexpr int NC2 = CI2 / 32;
    constexpr int NCH = (CI1 + CI2) / 32;
    constexpr int PANEL = NCH * NT * 512;
    constexpr int GSH   = G * PANEL;
    constexpr int NPH   = K / G;
    constexpr int WCH   = GSH / 4;
    constexpr int S16   = (WCH * 2) / 1024;
    constexpr int S4    = ((WCH * 2) % 1024) / 256;
    __shared__ __attribute__((aligned(16))) short sB[GSH];
    const int tid  = threadIdx.x;
    const int lane = tid & 63;
    const int wid  = tid >> 6;
    const int m    = lane & 15;
    const int quad = lane >> 4;
    const long long tb0 = ((long long)blockIdx.x * 4 + wid) * (MT * 16);

    f32x4 acc[MT][NT];
#pragma unroll
    for (int mt = 0; mt < MT; mt++)
#pragma unroll
        for (int t = 0; t < NT; t++) acc[mt][t] = (f32x4)0.f;

#define STAGE(ph)                                                              \
    {                                                                          \
        const short* _src = Wf + (size_t)(ph) * GSH + wid * WCH;               \
        short* _dst = &sB[wid * WCH];                                          \
        _Pragma("unroll")                                                      \
        for (int i = 0; i < S16; i++)                                          \
            __builtin_amdgcn_global_load_lds(                                  \
                (gas_short*)(_src + i * 512 + lane * 8),                       \
                (las_short*)(_dst + i * 512), 16, 0, 0);                       \
        _Pragma("unroll")                                                      \
        for (int i = 0; i < S4; i++)                                           \
            __builtin_amdgcn_global_load_lds(                                  \
                (gas_short*)(_src + S16 * 512 + i * 128 + lane * 2),           \
                (las_short*)(_dst + S16 * 512 + i * 128), 4, 0, 0);            \
    }

    STAGE(0)
    __builtin_amdgcn_sched_barrier(0);

    int idxs[MT][K];
#pragma unroll
    for (int mt = 0; mt < MT; mt++) {
        long long r = tb0 + mt * 16 + m;
        bool rv = r < N;
#pragma unroll
        for (int k = 0; k < K; k++)
            idxs[mt][k] = rv ? nbr[r * K + k] : -1;
    }
    unsigned pmask[MT];
#pragma unroll
    for (int mt = 0; mt < MT; mt++) {
        unsigned pm = 0;
#pragma unroll
        for (int k = 0; k < K; k++)
            pm |= __any(idxs[mt][k] >= 0) ? (1u << k) : 0u;
        pmask[mt] = __builtin_amdgcn_readfirstlane(pm);
    }

    float aS[FACT ? NC1 * 8 : 1], aBb[FACT ? NC1 * 8 : 1];
    if constexpr (FACT) {
#pragma unroll
        for (int c = 0; c < NC1; c++)
#pragma unroll
            for (int jj = 0; jj < 8; jj++) {
                int ch = c * 32 + quad * 8 + jj;
                aS[c * 8 + jj]  = abp[ch];
                aBb[c * 8 + jj] = abp[CI1 + ch];
            }
    }

    __builtin_amdgcn_sched_barrier(0);
    asm volatile("s_waitcnt vmcnt(0)" ::: "memory");
    __builtin_amdgcn_s_barrier();
    __builtin_amdgcn_sched_barrier(0);
    asm volatile("" ::: "memory");

    short8 S[3][NCH];

#define LOADS(sl, mt, kk)                                                      \
    {                                                                          \
        int _i = idxs[mt][kk];                                                 \
        long long _j = _i < 0 ? 0 : _i;                                        \
        _Pragma("unroll")                                                      \
        for (int c = 0; c < NC1; c++) {                                        \
            short8 _v = *reinterpret_cast<const short8*>(                      \
                fA + _j * CI1 + c * 32 + quad * 8);                            \
            if constexpr (FACT) {                                              \
                short8 _o;                                                     \
                _Pragma("unroll")                                              \
                for (int jj = 0; jj < 8; jj++) {                               \
                    float _f = b2f(_v[jj]) * aS[c * 8 + jj] + aBb[c * 8 + jj]; \
                    _o[jj] = f2b(_f > 0.f ? _f : 0.f);                         \
                }                                                              \
                _v = _o;                                                       \
            }                                                                  \
            S[sl][c] = (_i >= 0) ? _v : (short8)0;                             \
        }                                                                      \
        if constexpr (NC2 > 0) {                                               \
            _Pragma("unroll")                                                  \
            for (int c = 0; c < NC2; c++) {                                    \
                short8 _v = *reinterpret_cast<const short8*>(                  \
                    fB + _j * CI2 + c * 32 + quad * 8);                        \
                S[sl][NC1 + c] = (_i >= 0) ? _v : (short8)0;                   \
            }                                                                  \
        }                                                                      \
    }
#define MFMAS(sl, mt, jl)                                                      \
    {                                                                          \
        _Pragma("unroll")                                                      \
        for (int c = 0; c < NCH; c++) {                                        \
            _Pragma("unroll")                                                  \
            for (int t = 0; t < NT; t++) {                                     \
                short8 b = *reinterpret_cast<const short8*>(                   \
                    &sB[((jl) * NCH * NT + c * NT + t) * 512 + lane * 8]);     \
                acc[mt][t] = __builtin_amdgcn_mfma_f32_16x16x32_bf16(          \
                    S[sl][c], b, acc[mt][t], 0, 0, 0);                         \
            }                                                                  \
        }                                                                      \
    }

#pragma unroll
    for (int ph = 0; ph < NPH; ph++) {
#pragma unroll
        for (int mt = 0; mt < MT; mt++) {
            const unsigned mm = (pmask[mt] >> (ph * G)) & ((1u << G) - 1);
#pragma unroll
            for (int j = 0; j < G + 2; j++) {
                if (j < G)
                    if (mm & (1u << j)) LOADS(j % 3, mt, ph * G + j)
                if (j >= 2)
                    if (mm & (1u << (j - 2))) MFMAS((j - 2) % 3, mt, j - 2)
            }
        }
        if (ph + 1 < NPH) {
            __builtin_amdgcn_sched_barrier(0);
            asm volatile("s_waitcnt lgkmcnt(0)" ::: "memory");
            __builtin_amdgcn_s_barrier();
            __builtin_amdgcn_sched_barrier(0);
            STAGE(ph + 1)
            __builtin_amdgcn_sched_barrier(0);
            asm volatile("s_waitcnt vmcnt(0)" ::: "memory");
            __builtin_amdgcn_s_barrier();
            __builtin_amdgcn_sched_barrier(0);
            asm volatile("" ::: "memory");
        }
    }
#undef LOADS
#undef MFMAS
#undef STAGE
    float s[NT], q[NT];
#pragma unroll
    for (int t = 0; t < NT; t++) { s[t] = 0.f; q[t] = 0.f; }
#pragma unroll
    for (int mt = 0; mt < MT; mt++) {
#pragma unroll
        for (int g4 = 0; g4 < 4; g4++) {
            long long sr = tb0 + mt * 16 + quad * 4 + g4;
            if (sr < N) {
#pragma unroll
                for (int t = 0; t < NT; t++) {
                    float v = acc[mt][t][g4];
                    out[sr * COUT + t * 16 + m] = f2b(v);
                    s[t] += v; q[t] += v * v;
                }
            }
        }
    }
    float* pb = pstat + (blockIdx.x & 7) * 2 * COUT;
#pragma unroll
    for (int t = 0; t < NT; t++) {
        float sv = s[t], qv = q[t];
        sv += __shfl_xor(sv, 16); qv += __shfl_xor(qv, 16);
        sv += __shfl_xor(sv, 32); qv += __shfl_xor(qv, 32);
        if (quad == 0) {
            atomicAdd(&pb[t * 16 + m], sv);
            atomicAdd(&pb[COUT + t * 16 + m], qv);
        }
    }
}

// ---------- MFMA up conv v10 (R24, unchanged) ------------------------------
template<int CIN, int COUT, int G>
__global__ __launch_bounds__(256) void upmfma10(
    const short* __restrict__ f, const int* __restrict__ rb,
    const short* __restrict__ Wf, short* __restrict__ out,
    float* __restrict__ pstat, const float* __restrict__ abp, int N) {
    static_assert(8 % G == 0, "G must divide 8");
    constexpr int NT = COUT / 16;
    constexpr int NK = CIN / 32;
    constexpr int PANEL = NK * NT * 512;
    constexpr int GSH   = G * PANEL;
    constexpr int NPH   = 8 / G;
    constexpr int WCH   = GSH / 4;
    constexpr int S16   = (WCH * 2) / 1024;
    constexpr int S4    = ((WCH * 2) % 1024) / 256;
    __shared__ __attribute__((aligned(16))) short sB[GSH];
    const int tid  = threadIdx.x;
    const int lane = tid & 63;
    const int wid  = tid >> 6;
    const int m    = lane & 15;
    const int quad = lane >> 4;
    const long long row0 = ((long long)blockIdx.x * 4 + wid) * 16;
    const long long r = row0 + m;
    const bool rv = r < N;
    const long long rc = rv ? r : 0;

#define STAGE(ph)                                                              \
    {                                                                          \
        const short* _src = Wf + (size_t)(ph) * GSH + wid * WCH;               \
        short* _dst = &sB[wid * WCH];                                          \
        _Pragma("unroll")                                                      \
        for (int i = 0; i < S16; i++)                                          \
            __builtin_amdgcn_global_load_lds(                                  \
                (gas_short*)(_src + i * 512 + lane * 8),                       \
                (las_short*)(_dst + i * 512), 16, 0, 0);                       \
        _Pragma("unroll")                                                      \
        for (int i = 0; i < S4; i++)                                           \
            __builtin_amdgcn_global_load_lds(                                  \
                (gas_short*)(_src + S16 * 512 + i * 128 + lane * 2),           \
                (las_short*)(_dst + S16 * 512 + i * 128), 4, 0, 0);            \
    }
    STAGE(0)
    __builtin_amdgcn_sched_barrier(0);

    short8 af[NK];
#pragma unroll
    for (int kc = 0; kc < NK; kc++) {
        short8 v = *reinterpret_cast<const short8*>(
            f + rc * CIN + kc * 32 + quad * 8);
        short8 o;
#pragma unroll
        for (int jj = 0; jj < 8; jj++) {
            int ch = kc * 32 + quad * 8 + jj;
            float u = b2f(v[jj]) * abp[ch] + abp[CIN + ch];
            o[jj] = f2b(u > 0.f ? u : 0.f);
        }
        af[kc] = rv ? o : (short8)0;
    }
    int sidx[8][4];
#pragma unroll
    for (int g4 = 0; g4 < 4; g4++) {
        long long sr = row0 + quad * 4 + g4;
#pragma unroll
        for (int k = 0; k < 8; k++)
            sidx[k][g4] = (sr < N) ? rb[sr * 8 + k] : -1;
    }
    unsigned pm = 0;
#pragma unroll
    for (int k = 0; k < 8; k++) {
        int anyv = (sidx[k][0] >= 0) | (sidx[k][1] >= 0) |
                   (sidx[k][2] >= 0) | (sidx[k][3] >= 0);
        pm |= __any(anyv) ? (1u << k) : 0u;
    }
    pm = __builtin_amdgcn_readfirstlane(pm);

    float s[NT], q[NT];
#pragma unroll
    for (int t = 0; t < NT; t++) { s[t] = 0.f; q[t] = 0.f; }

    __builtin_amdgcn_sched_barrier(0);
    asm volatile("s_waitcnt vmcnt(0)" ::: "memory");
    __builtin_amdgcn_s_barrier();
    __builtin_amdgcn_sched_barrier(0);
    asm volatile("" ::: "memory");

#pragma unroll
    for (int ph = 0; ph < NPH; ph++) {
#pragma unroll
        for (int j = 0; j < G; j++) {
            const int k = ph * G + j;
            if (pm & (1u << k)) {
                f32x4 acc[NT];
#pragma unroll
                for (int t = 0; t < NT; t++) acc[t] = (f32x4)0.f;
#pragma unroll
                for (int kc = 0; kc < NK; kc++) {
#pragma unroll
                    for (int t = 0; t < NT; t++) {
                        short8 b = *reinterpret_cast<const short8*>(
                            &sB[(j * NK * NT + kc * NT + t) * 512 + lane * 8]);
                        acc[t] = __builtin_amdgcn_mfma_f32_16x16x32_bf16(
                            af[kc], b, acc[t], 0, 0, 0);
                    }
                }
#pragma unroll
                for (int g4 = 0; g4 < 4; g4++) {
                    if (sidx[k][g4] >= 0) {
#pragma unroll
                        for (int t = 0; t < NT; t++) {
                            float v = acc[t][g4];
                            out[(long long)sidx[k][g4] * COUT + t * 16 + m] =
                                f2b(v);
                            s[t] += v; q[t] += v * v;
                        }
                    }
                }
            }
        }
        if (ph + 1 < NPH) {
            __builtin_amdgcn_sched_barrier(0);
            asm volatile("s_waitcnt lgkmcnt(0)" ::: "memory");
            __builtin_amdgcn_s_barrier();
            __builtin_amdgcn_sched_barrier(0);
            STAGE(ph + 1)
            __builtin_amdgcn_sched_barrier(0);
            asm volatile("s_waitcnt vmcnt(0)" ::: "memory");
            __builtin_amdgcn_s_barrier();
            __builtin_amdgcn_sched_barrier(0);
            asm volatile("" ::: "memory");
        }
    }
#undef STAGE
    float* pb = pstat + (blockIdx.x & 7) * 2 * COUT;
#pragma unroll
    for (int t = 0; t < NT; t++) {
        float sv = s[t], qv = q[t];
        sv += __shfl_xor(sv, 16); qv += __shfl_xor(qv, 16);
        sv += __shfl_xor(sv, 32); qv += __shfl_xor(qv, 32);
        if (quad == 0) {
            atomicAdd(&pb[t * 16 + m], sv);
            atomicAdd(&pb[COUT + t * 16 + m], qv);
        }
    }
}

// ---------- BN stats (only for conv_in's output), f64 deterministic --------
template<int C>
__global__ void bn_stats(const short* __restrict__ x, double* __restrict__ part, int N) {
    constexpr int GR  = C / 8;
    constexpr int RPB = 256 / GR;
    constexpr int ACTIVE = GR * RPB;
    __shared__ double ls[256 * 8];
    __shared__ double lq[256 * 8];
    const int tid = threadIdx.x;
    const int g   = tid % GR;
    const int rr  = tid / GR;
    double s[8], q[8];
#pragma unroll
    for (int j = 0; j < 8; j++) { s[j] = 0.0; q[j] = 0.0; }
    if (tid < ACTIVE) {
        for (long long r = (long long)blockIdx.x * RPB + rr; r < N;
             r += (long long)gridDim.x * RPB) {
            short8 v = *reinterpret_cast<const short8*>(x + r * C + g * 8);
#pragma unroll
            for (int j = 0; j < 8; j++) {
                double f = (double)b2f(v[j]);
                s[j] += f; q[j] += f * f;
            }
        }
    }
#pragma unroll
    for (int j = 0; j < 8; j++) { ls[tid * 8 + j] = s[j]; lq[tid * 8 + j] = q[j]; }
    __syncthreads();
    if (tid < C) {
        int gg = tid / 8, jj = tid % 8;
        double S = 0.0, Q = 0.0;
        for (int r2 = 0; r2 < RPB; r2++) {
            S += ls[(r2 * GR + gg) * 8 + jj];
            Q += lq[(r2 * GR + gg) * 8 + jj];
        }
        part[blockIdx.x * 256 + tid]       = S;
        part[blockIdx.x * 256 + 128 + tid] = Q;
    }
}

__global__ void bn_fin(const double* __restrict__ part, const float* __restrict__ gb,
                       int gbfull, int goff, float* __restrict__ ab,
                       int C, int P, double invN) {
    __shared__ double ss[256], sq[256];
    const int tid = threadIdx.x;
    const int c   = tid % C;
    const int g   = tid / C;
    const int G   = 256 / C;
    double s = 0.0, q = 0.0;
    if (g < G) {
        for (int p = g; p < P; p += G) {
            s += part[p * 256 + c];
            q += part[p * 256 + 128 + c];
        }
    }
    ss[tid] = s; sq[tid] = q;
    __syncthreads();
    if (tid < C) {
        for (int j = 1; j < G; j++) { s += ss[j * C + c]; q += sq[j * C + c]; }
        double mu  = s * invN;
        double var = q * invN - mu * mu;
        double a   = (double)gb[goff + c] / sqrt(var + 1e-4);
        ab[c]     = (float)a;
        ab[C + c] = (float)((double)gb[gbfull + goff + c] - mu * a);
    }
}

// ---------- bn_fin_a: reduce 8 atomic banks -> ab --------------------------
__global__ void bn_fin_a(const float* __restrict__ pst, const float* __restrict__ gb,
                         int gbfull, int goff, float* __restrict__ ab,
                         int C, double invN) {
    int c = threadIdx.x;
    if (c >= C) return;
    double s = 0.0, q = 0.0;
#pragma unroll
    for (int b = 0; b < 8; b++) {
        s += (double)pst[b * 2 * C + c];
        q += (double)pst[b * 2 * C + C + c];
    }
    double mu  = s * invN;
    double var = q * invN - mu * mu;
    double a   = (double)gb[goff + c] / sqrt(var + 1e-4);
    ab[c]     = (float)a;
    ab[C + c] = (float)((double)gb[gbfull + goff + c] - mu * a);
}

// ---------- bnact: y = relu(x*a + b), bf16 -> bf16, 8 elems/thread ---------
template<int C>
__global__ void bnact(const short* __restrict__ x, const float* __restrict__ ab,
                      short* __restrict__ y, long long total8) {
    long long i = (long long)blockIdx.x * blockDim.x + threadIdx.x;
    if (i >= total8) return;
    long long base = i * 8;
    int c0 = (int)(base % C);
    short8 v = *reinterpret_cast<const short8*>(x + base);
    short8 o;
#pragma unroll
    for (int j = 0; j < 8; j++) {
        float f = b2f(v[j]) * ab[c0 + j] + ab[C + c0 + j];
        o[j] = f2b(f > 0.f ? f : 0.f);
    }
    *reinterpret_cast<short8*>(y + base) = o;
}

// ---------- bnact2: two tensors in one launch ------------------------------
template<int C>
__global__ void bnact2(const short* __restrict__ xa, const float* __restrict__ aba,
                       short* __restrict__ ya,
                       const short* __restrict__ xb, const float* __restrict__ abb,
                       short* __restrict__ yb, long long n8) {
    long long i = (long long)blockIdx.x * blockDim.x + threadIdx.x;
    if (i >= 2 * n8) return;
    const short* x; const float* ab; short* y; long long ii;
    if (i < n8) { x = xa; ab = aba; y = ya; ii = i; }
    else        { x = xb; ab = abb; y = yb; ii = i - n8; }
    long long base = ii * 8;
    int c0 = (int)(base % C);
    short8 v = *reinterpret_cast<const short8*>(x + base);
    short8 o;
#pragma unroll
    for (int j = 0; j < 8; j++) {
        float f = b2f(v[j]) * ab[c0 + j] + ab[C + c0 + j];
        o[j] = f2b(f > 0.f ? f : 0.f);
    }
    *reinterpret_cast<short8*>(y + base) = o;
}

// ---------- final linear (bnf fused), bf16 in, f32 out ---------------------
__global__ void final_k(const short* __restrict__ x, const float* __restrict__ ab,
                        const float* __restrict__ lw, const float* __restrict__ lb,
                        float* __restrict__ out, int N) {
    long long r = (long long)blockIdx.x * blockDim.x + threadIdx.x;
    if (r >= N) return;
    float a0 = lb[0], a1 = lb[1];
#pragma unroll
    for (int j = 0; j < 4; j++) {
        short8 v = *reinterpret_cast<const short8*>(x + r * 32 + j * 8);
#pragma unroll
        for (int t = 0; t < 8; t++) {
            int ci = 8 * j + t;
            float u = b2f(v[t]) * ab[ci] + ab[32 + ci];
            u = u > 0.f ? u : 0.f;
            a0 += u * lw[ci * 2];
            a1 += u * lw[ci * 2 + 1];
        }
    }
    out[2 * r]     = a0;
    out[2 * r + 1] = a1;
}

extern "C" void kernel_launch(void* const* d_in, const int* in_sizes, int n_in,
                              void* d_out, int out_size, void* d_ws, size_t ws_size,
                              hipStream_t stream) {
    const long long N0 = in_sizes[0] / 3;
    const long long N1 = in_sizes[26] / 8;
    const long long N2 = in_sizes[27] / 8;
    const int P = 256;

    const float* feat = (const float*)d_in[0];
    const int* nbr0 = (const int*)d_in[23];
    const int* nbr1 = (const int*)d_in[24];
    const int* nbr2 = (const int*)d_in[25];
    const int* rb0  = (const int*)d_in[26];
    const int* rb1  = (const int*)d_in[27];

    // ---- arena ----
    char* p = (char*)d_ws;
    double* part = (double*)p;            p += (size_t)P * 256 * 8;     // 512 KB
    float*  ab   = (float*)p;             p += 12 * 256 * 4;
    float*  pst  = (float*)p;             p += (size_t)10 * 2048 * 4;
    unsigned* msk0 = (unsigned*)p;        p += ((size_t)N0 * 4 + 63) & ~(size_t)63;
    const int wLayer[9] = {3, 5, 7, 9, 11, 13, 15, 17, 19};
    const int wK[9]  = {27, 8, 27, 8, 27, 8, 27, 8, 27};
    const int wCI[9] = {32, 32, 64, 64, 96, 96, 128, 64, 64};
    const int wCO[9] = {32, 64, 64, 96, 96, 64, 64, 32, 32};
    short* wt[9];
    WPA wpa;
    int cum = 0;
    for (int i = 0; i < 9; i++) {
        wt[i] = (short*)p;
        int n = wK[i] * wCI[i] * wCO[i];
        p += (((size_t)n * 2 + 63) & ~(size_t)63);
        wpa.src[i] = (const float*)d_in[wLayer[i]];
        wpa.dst[i] = wt[i];
        wpa.CI[i] = wCI[i]; wpa.CO[i] = wCO[i];
        wpa.cum[i] = cum; cum += n;
    }
    wpa.cum[9] = cum;
    auto balloc = [&](long long elems) {
        short* q = (short*)p;
        p += (((size_t)elems * 2 + 63) & ~(size_t)63);
        return q;
    };
    short* R0 = balloc(N0 * 32);   // t0 / d0 / d1 / u1 / u0 (raw)
    short* R1 = balloc(N0 * 32);   // x0 raw (persist)
    short* R2 = balloc(N1 * 64);   // x1 raw (persist)
    short* R3 = balloc(N0 * 32);   // x2 / y1 / y0 (raw)
    short* Xb = balloc(N0 * 32);   // act out #1
    short* Yb = balloc(N0 * 32);   // act out #2

    wprep_all<<<(cum + 255) / 256, 256, 0, stream>>>(wpa, cum);
    zerok<<<(10 * 2048 + 255) / 256, 256, 0, stream>>>(pst, 10 * 2048);
    nbrmask_k<<<(int)((N0 + 255) / 256), 256, 0, stream>>>(nbr0, msk0, (int)N0);

#define AB(SL) (ab + (SL) * 256)
#define PS(SL) (pst + (SL) * 2048)
#define FINA(PSL, GBI, GBFULL, GOFF, SL, CH, NN)                                     \
    bn_fin_a<<<1, 128, 0, stream>>>(PS(PSL), (const float*)d_in[GBI], GBFULL, GOFF,  \
                                    AB(SL), CH, 1.0 / (double)(NN))
#define GB1(N_) (int)(((N_) + 63) / 64)
#define GB2(N_) (int)(((N_) + 127) / 128)

    // ---- level 0 ----
    conv_in<<<(int)((N0 + 255) / 256), 256, 0, stream>>>(
        feat, nbr0, (const float*)d_in[1], R0, (int)N0);                  // t0 -> R0
    bn_stats<32><<<P, 256, 0, stream>>>(R0, part, (int)N0);               // bn1_0
    bn_fin<<<1, 256, 0, stream>>>(part, (const float*)d_in[2], 32, 0,
                                  AB(0), 32, P, 1.0 / (double)N0);
    stencil0<32, 0, 32><<<GB2(N0), 256, 0, stream>>>(
        R0, nullptr, msk0, wt[0], R1, PS(0), AB(0), nullptr, (int)N0);    // x0 -> R1
    FINA(0, 4, 32, 0, 1, 32, N0);                                         // bnd_0
    FINA(0, 18, 64, 0, 9, 32, N0);                                        // bn2_0[x0]
    gmfma10<32, 0, 64, 8, 8, 2, true><<<GB2(N1), 256, 0, stream>>>(
        R1, nullptr, rb0, wt[1], R0, PS(1), AB(1), (int)N1);              // d0 -> R0
    FINA(1, 6, 64, 0, 2, 64, N1);                                         // bn1_1

    // ---- level 1 ----
    bnact<64><<<(int)((N1 * 64 / 8 + 255) / 256), 256, 0, stream>>>(
        R0, AB(2), Xb, N1 * 64 / 8);
    gmfma10<64, 0, 64, 27, 3, 2, false><<<GB2(N1), 256, 0, stream>>>(
        Xb, nullptr, nbr1, wt[2], R2, PS(2), nullptr, (int)N1);           // x1 -> R2
    FINA(2, 8, 64, 0, 3, 64, N1);                                         // bnd_1
    FINA(2, 14, 128, 0, 6, 64, N1);                                       // bn2_1[x1]
    gmfma10<64, 0, 96, 8, 2, 1, true><<<GB1(N2), 256, 0, stream>>>(
        R2, nullptr, rb1, wt[3], R0, PS(3), AB(3), (int)N2);              // d1 -> R0
    FINA(3, 10, 96, 0, 4, 96, N2);                                        // bn1_2

    // ---- level 2 ----
    bnact<96><<<(int)((N2 * 96 / 8 + 255) / 256), 256, 0, stream>>>(
        R0, AB(4), Xb, N2 * 96 / 8);
    gmfma10<96, 0, 96, 27, 3, 1, false><<<GB1(N2), 256, 0, stream>>>(
        Xb, nullptr, nbr2, wt[4], R3, PS(4), nullptr, (int)N2);           // x2 -> R3
    FINA(4, 12, 96, 0, 5, 96, N2);                                        // bnu_1

    // ---- up to level 1 ----
    upmfma10<96, 64, 2><<<GB1(N2), 256, 0, stream>>>(
        R3, rb1, wt[5], R0, PS(5), AB(5), (int)N2);                       // u1 -> R0
    FINA(5, 14, 128, 64, 7, 64, N1);                                      // bn2_1[u1]
    bnact2<64><<<(int)((2 * (N1 * 64 / 8) + 255) / 256), 256, 0, stream>>>(
        R2, AB(6), Xb, R0, AB(7), Yb, N1 * 64 / 8);
    gmfma10<64, 64, 64, 27, 3, 2, false><<<GB2(N1), 256, 0, stream>>>(
        Xb, Yb, nbr1, wt[6], R3, PS(6), nullptr, (int)N1);                // y1 -> R3
    FINA(6, 16, 64, 0, 8, 64, N1);                                        // bnu_0

    // ---- up to level 0 ----
    upmfma10<64, 32, 4><<<GB1(N1), 256, 0, stream>>>(
        R3, rb0, wt[7], R0, PS(7), AB(8), (int)N1);                       // u0 -> R0
    FINA(7, 18, 64, 32, 10, 32, N0);                                      // bn2_0[u0]
    stencil0<32, 32, 32><<<GB2(N0), 256, 0, stream>>>(
        R1, R0, msk0, wt[8], R3, PS(8), AB(9), AB(10), (int)N0);          // y0 -> R3
    FINA(8, 20, 32, 0, 11, 32, N0);                                       // bnf

    final_k<<<(int)((N0 + 255) / 256), 256, 0, stream>>>(
        R3, AB(11), (const float*)d_in[21], (const float*)d_in[22],
        (float*)d_out, (int)N0);

#undef AB
#undef PS
#undef FINA
#undef GB1
#undef GB2
}